// Round 1
// baseline (1096.918 us; speedup 1.0000x reference)
//
#include <hip/hip_runtime.h>
#include <hip/hip_bf16.h>
#include <stdint.h>

typedef float  f32x4 __attribute__((ext_vector_type(4)));
typedef float  f4    __attribute__((ext_vector_type(4)));
typedef short  s16x8 __attribute__((ext_vector_type(8)));

#define T_LEN  4096
#define NHEAD  16
#define DHEAD  64
#define QBLK   128
#define KVBLK  64

__device__ __forceinline__ ushort f2bf(float x){
  uint32_t u = __builtin_bit_cast(uint32_t, x);
  u += 0x7FFFu + ((u >> 16) & 1u);   // RNE
  return (ushort)(u >> 16);
}

__global__ void alibi_attn_kernel(const float* __restrict__ Qg,
                                  const float* __restrict__ Kg,
                                  const float* __restrict__ Vg,
                                  float* __restrict__ Og)
{
  __shared__ ushort kbuf[KVBLK * DHEAD];      // [key][d], swizzled
  __shared__ ushort vbuf[DHEAD * KVBLK];      // [d][key], swizzled (transposed)
  __shared__ ushort pbuf[4 * 32 * KVBLK];     // per-wave P [q][k], swizzled

  // XCD-aware bijective swizzle: 512 blocks -> each XCD gets 2 consecutive heads
  const int bid = blockIdx.x;
  const int fid = (bid & 7) * 64 + (bid >> 3);
  const int h   = fid >> 5;     // /32 q-tiles per head
  const int qt  = fid & 31;

  const int tid  = threadIdx.x;
  const int wave = tid >> 6;
  const int lane = tid & 63;
  const int lg   = lane >> 4;   // 0..3
  const int ln   = lane & 15;   // 0..15

  const int qb = qt * QBLK + wave * 32;       // this wave's q base (owns 32 rows)
  const float slope = exp2f(-0.5f * (float)(h + 1));
  const float cs = 0.125f * 1.44269504089f;   // 1/sqrt(64) * log2(e)
  const float bs = slope * 1.44269504089f;    // slope * log2(e)

  const size_t headoff = (size_t)h * T_LEN * DHEAD;

  // ---- Q fragments (A-operand): row = ln, k = dh*32 + lg*8 + j ----
  s16x8 qf[2][2];
#pragma unroll
  for (int rg = 0; rg < 2; ++rg)
#pragma unroll
    for (int dh = 0; dh < 2; ++dh){
      const float* qp = Qg + headoff + (size_t)(qb + rg*16 + ln) * DHEAD + dh*32 + lg*8;
      f4 x = *(const f4*)qp;
      f4 y = *(const f4*)(qp + 4);
      s16x8 t;
      t[0]=(short)f2bf(x[0]); t[1]=(short)f2bf(x[1]); t[2]=(short)f2bf(x[2]); t[3]=(short)f2bf(x[3]);
      t[4]=(short)f2bf(y[0]); t[5]=(short)f2bf(y[1]); t[6]=(short)f2bf(y[2]); t[7]=(short)f2bf(y[3]);
      qf[rg][dh] = t;
    }

  f32x4 acc[2][4];
  f32x4 mreg[2], lreg[2];
#pragma unroll
  for (int rg = 0; rg < 2; ++rg){
    mreg[rg] = (f32x4)(-1e30f);
    lreg[rg] = (f32x4)(0.0f);
#pragma unroll
    for (int dt = 0; dt < 4; ++dt) acc[rg][dt] = (f32x4)(0.0f);
  }

  ushort* pw = &pbuf[wave * 32 * KVBLK];

  for (int kv = 0; kv < T_LEN / KVBLK; ++kv){
    const int kbase = kv * KVBLK;
    __syncthreads();

    // ---------------- stage K and V tiles (fp32 -> bf16) ----------------
    if (tid < 128){
      // V transposed: vbuf[d][k], 2 keys packed per 4B write
      const int k0  = (tid >> 2) * 2;
      const int seg = (tid & 3) * 16;
      const float* vp = Vg + headoff + (size_t)(kbase + k0) * DHEAD + seg;
      float av[16], bv[16];
      *(f4*)&av[0]  = *(const f4*)(vp);
      *(f4*)&av[4]  = *(const f4*)(vp + 4);
      *(f4*)&av[8]  = *(const f4*)(vp + 8);
      *(f4*)&av[12] = *(const f4*)(vp + 12);
      *(f4*)&bv[0]  = *(const f4*)(vp + 64);
      *(f4*)&bv[4]  = *(const f4*)(vp + 68);
      *(f4*)&bv[8]  = *(const f4*)(vp + 72);
      *(f4*)&bv[12] = *(const f4*)(vp + 76);
#pragma unroll
      for (int i = 0; i < 16; ++i){
        const int d = seg + i;
        uint32_t pr = (uint32_t)f2bf(av[i]) | ((uint32_t)f2bf(bv[i]) << 16);
        const int idx = (d * 64 + k0) ^ ((d & 7) << 3);
        *(uint32_t*)&vbuf[idx] = pr;
      }
    } else {
      // K row-major: kbuf[key][d]
      const int tt  = tid - 128;
      const int row = tt >> 1;
      const int seg = (tt & 1) * 32;
      const float* kp = Kg + headoff + (size_t)(kbase + row) * DHEAD + seg;
      float kl[32];
#pragma unroll
      for (int j = 0; j < 8; ++j) *(f4*)&kl[j*4] = *(const f4*)(kp + j*4);
#pragma unroll
      for (int i = 0; i < 4; ++i){
        s16x8 t;
#pragma unroll
        for (int j = 0; j < 8; ++j) t[j] = (short)f2bf(kl[i*8 + j]);
        const int idx = (row * 64 + seg + i*8) ^ ((row & 7) << 3);
        *(s16x8*)&kbuf[idx] = t;
      }
    }
    __syncthreads();

    // ---------------- QK^T ----------------
    s16x8 kf[4][2];
#pragma unroll
    for (int kt = 0; kt < 4; ++kt){
      const int key = kt * 16 + ln;
#pragma unroll
      for (int dh = 0; dh < 2; ++dh){
        const int idx = (key * 64 + dh*32 + lg*8) ^ ((key & 7) << 3);
        kf[kt][dh] = *(const s16x8*)&kbuf[idx];
      }
    }
    f32x4 S[2][4];
#pragma unroll
    for (int rg = 0; rg < 2; ++rg)
#pragma unroll
      for (int kt = 0; kt < 4; ++kt){
        f32x4 c = (f32x4)(0.0f);
        c = __builtin_amdgcn_mfma_f32_16x16x32_bf16(qf[rg][0], kf[kt][0], c, 0, 0, 0);
        c = __builtin_amdgcn_mfma_f32_16x16x32_bf16(qf[rg][1], kf[kt][1], c, 0, 0, 0);
        S[rg][kt] = c;
      }

    // ---------------- bias + online softmax ----------------
#pragma unroll
    for (int rg = 0; rg < 2; ++rg){
      const int qrow0 = qb + rg*16 + lg*4;   // absolute q position of r=0
#pragma unroll
      for (int r = 0; r < 4; ++r){
        float mx = -1e30f;
#pragma unroll
        for (int kt = 0; kt < 4; ++kt){
          const int kpos = kbase + kt*16 + ln;
          const float dist = fabsf((float)(qrow0 + r - kpos));
          const float s = fmaf(-bs, dist, S[rg][kt][r] * cs);
          S[rg][kt][r] = s;
          mx = fmaxf(mx, s);
        }
        mx = fmaxf(mx, __shfl_xor(mx, 1, 64));
        mx = fmaxf(mx, __shfl_xor(mx, 2, 64));
        mx = fmaxf(mx, __shfl_xor(mx, 4, 64));
        mx = fmaxf(mx, __shfl_xor(mx, 8, 64));

        const float mold = mreg[rg][r];
        const float mnew = fmaxf(mold, mx);
        const float sc   = exp2f(mold - mnew);
        float sum = 0.f;
#pragma unroll
        for (int kt = 0; kt < 4; ++kt){
          const float p = exp2f(S[rg][kt][r] - mnew);
          S[rg][kt][r] = p;
          sum += p;
        }
        sum += __shfl_xor(sum, 1, 64);
        sum += __shfl_xor(sum, 2, 64);
        sum += __shfl_xor(sum, 4, 64);
        sum += __shfl_xor(sum, 8, 64);
        lreg[rg][r] = lreg[rg][r] * sc + sum;
        mreg[rg][r] = mnew;
#pragma unroll
        for (int dt = 0; dt < 4; ++dt) acc[rg][dt][r] *= sc;
      }
      // write P (bf16) to per-wave LDS region, C-layout -> [q][k] swizzled
#pragma unroll
      for (int kt = 0; kt < 4; ++kt)
#pragma unroll
        for (int r = 0; r < 4; ++r){
          const int qrow = rg*16 + lg*4 + r;
          const int idx = (qrow * 64 + kt*16 + ln) ^ ((qrow & 7) << 3);
          pw[idx] = f2bf(S[rg][kt][r]);
        }
    }
    asm volatile("s_waitcnt lgkmcnt(0)" ::: "memory");  // wave-local P writes -> reads

    // ---------------- PV ----------------
    s16x8 pf[2][2];
#pragma unroll
    for (int rg = 0; rg < 2; ++rg)
#pragma unroll
      for (int kh = 0; kh < 2; ++kh){
        const int row = rg*16 + ln;
        const int idx = (row * 64 + kh*32 + lg*8) ^ ((row & 7) << 3);
        pf[rg][kh] = *(const s16x8*)&pw[idx];
      }
#pragma unroll
    for (int dt = 0; dt < 4; ++dt){
      const int d = dt*16 + ln;
#pragma unroll
      for (int kh = 0; kh < 2; ++kh){
        const int idx = (d * 64 + kh*32 + lg*8) ^ ((d & 7) << 3);
        const s16x8 vf = *(const s16x8*)&vbuf[idx];
#pragma unroll
        for (int rg = 0; rg < 2; ++rg)
          acc[rg][dt] = __builtin_amdgcn_mfma_f32_16x16x32_bf16(pf[rg][kh], vf, acc[rg][dt], 0, 0, 0);
      }
    }
  }

  // ---------------- epilogue: normalize + store fp32 ----------------
#pragma unroll
  for (int rg = 0; rg < 2; ++rg)
#pragma unroll
    for (int r = 0; r < 4; ++r){
      const float inv = 1.0f / lreg[rg][r];
      const size_t rowoff = headoff + (size_t)(qb + rg*16 + lg*4 + r) * DHEAD;
#pragma unroll
      for (int dt = 0; dt < 4; ++dt)
        Og[rowoff + dt*16 + ln] = acc[rg][dt][r] * inv;
    }
}

extern "C" void kernel_launch(void* const* d_in, const int* in_sizes, int n_in,
                              void* d_out, int out_size, void* d_ws, size_t ws_size,
                              hipStream_t stream)
{
  const float* Q = (const float*)d_in[0];
  const float* K = (const float*)d_in[1];
  const float* V = (const float*)d_in[2];
  float* O = (float*)d_out;
  dim3 grid(T_LEN / QBLK * NHEAD);   // 512 blocks
  dim3 block(256);
  hipLaunchKernelGGL(alibi_attn_kernel, grid, block, 0, stream, Q, K, V, O);
}

// Round 3
// 212.206 us; speedup vs baseline: 5.1691x; 5.1691x over previous
//
#include <hip/hip_runtime.h>
#include <hip/hip_bf16.h>
#include <stdint.h>

typedef float f4    __attribute__((ext_vector_type(4)));
typedef float f32x4 __attribute__((ext_vector_type(4)));
typedef short s16x8 __attribute__((ext_vector_type(8)));
typedef short s16x4 __attribute__((ext_vector_type(4)));

#define T_LEN 4096
#define NHEAD 16
#define DHEAD 64
#define QBLK  128
#define KVBLK 64
#define NT    (T_LEN / KVBLK)

__device__ __forceinline__ ushort f2bf(float x){
  uint32_t u = __builtin_bit_cast(uint32_t, x);
  u += 0x7FFFu + ((u >> 16) & 1u);   // RNE
  return (ushort)(u >> 16);
}
__device__ __forceinline__ uint32_t cvt2(float a, float b){
  return (uint32_t)f2bf(a) | ((uint32_t)f2bf(b) << 16);
}
__device__ __forceinline__ int sw(int r){ return ((r ^ (r >> 3)) & 7) << 3; }

__global__ __launch_bounds__(256, 2)
void alibi_attn_kernel(const float* __restrict__ Qg,
                       const float* __restrict__ Kg,
                       const float* __restrict__ Vg,
                       float* __restrict__ Og)
{
  __shared__ ushort kbuf[2][KVBLK * DHEAD];   // [key][d] bf16, swizzled
  __shared__ ushort vbuf[2][DHEAD * KVBLK];   // [d][key] bf16, swizzled

  // XCD-aware bijective swizzle: 512 blocks, 8 XCDs -> 2 heads per XCD
  const int bid = blockIdx.x;
  const int fid = (bid & 7) * 64 + (bid >> 3);
  const int h  = fid >> 5;
  const int qt = fid & 31;

  const int tid  = threadIdx.x;
  const int wave = tid >> 6;
  const int lane = tid & 63;
  const int lg   = lane >> 4;
  const int ln   = lane & 15;

  const int qb = qt * QBLK + wave * 32;
  const float slope = exp2f(-0.5f * (float)(h + 1));
  const float cs = 0.125f * 1.44269504089f;    // 1/sqrt(64)*log2(e), folded into Q
  const float bs = slope * 1.44269504089f;
  const size_t headoff = (size_t)h * T_LEN * DHEAD;

  // ---- Q fragments (B-operand of swapped QK^T): lane ln = q, k = dh*32+lg*8+j ----
  s16x8 qf[2][2];
#pragma unroll
  for (int rg = 0; rg < 2; ++rg)
#pragma unroll
    for (int dh = 0; dh < 2; ++dh){
      const float* qp = Qg + headoff + (size_t)(qb + rg*16 + ln) * DHEAD + dh*32 + lg*8;
      f4 x = *(const f4*)qp;
      f4 y = *(const f4*)(qp + 4);
      union { uint32_t w[4]; s16x8 v; } u;
      u.w[0] = cvt2(x[0]*cs, x[1]*cs);
      u.w[1] = cvt2(x[2]*cs, x[3]*cs);
      u.w[2] = cvt2(y[0]*cs, y[1]*cs);
      u.w[3] = cvt2(y[2]*cs, y[3]*cs);
      qf[rg][dh] = u.v;
    }

  f32x4 acc[2][4];
#pragma unroll
  for (int rg = 0; rg < 2; ++rg)
#pragma unroll
    for (int dt = 0; dt < 4; ++dt) acc[rg][dt] = (f32x4)(0.0f);
  float mreg[2] = {-1e30f, -1e30f};
  float lreg[2] = {0.0f, 0.0f};
  const float qposf[2] = {(float)(qb + ln), (float)(qb + 16 + ln)};
  const float koffb = (float)(lg * 4);

  // staging: waves 0,1 (tid<128) handle V; waves 2,3 handle K
  f4 st4[8];
  const int vk0  = (tid >> 2) * 2;         // key pair base (V threads)
  const int vseg = (tid & 3) * 16;         // d segment     (V threads)
  const int krow = (tid - 128) >> 1;       // key row       (K threads)
  const int kseg = ((tid - 128) & 1) * 32; // d segment     (K threads)
  const float* Vb = Vg + headoff;
  const float* Kb = Kg + headoff;

  auto stage_load = [&](int kv){
    const int kb = kv * KVBLK;
    if (tid < 128){
      const float* vp = Vb + (size_t)(kb + vk0) * DHEAD + vseg;
      st4[0] = *(const f4*)(vp);      st4[1] = *(const f4*)(vp + 4);
      st4[2] = *(const f4*)(vp + 8);  st4[3] = *(const f4*)(vp + 12);
      st4[4] = *(const f4*)(vp + 64); st4[5] = *(const f4*)(vp + 68);
      st4[6] = *(const f4*)(vp + 72); st4[7] = *(const f4*)(vp + 76);
    } else {
      const float* kp = Kb + (size_t)(kb + krow) * DHEAD + kseg;
#pragma unroll
      for (int j = 0; j < 8; ++j) st4[j] = *(const f4*)(kp + j*4);
    }
  };
  auto stage_store = [&](int b){
    if (tid < 128){
#pragma unroll
      for (int i = 0; i < 16; ++i){
        const int d = vseg + i;
        uint32_t pr = cvt2(st4[i>>2][i&3], st4[4 + (i>>2)][i&3]);
        *(uint32_t*)&vbuf[b][(d*64 + vk0) ^ sw(d)] = pr;
      }
    } else {
#pragma unroll
      for (int i = 0; i < 4; ++i){
        union { uint32_t w[4]; s16x8 v; } u;
        u.w[0] = cvt2(st4[i*2][0],   st4[i*2][1]);
        u.w[1] = cvt2(st4[i*2][2],   st4[i*2][3]);
        u.w[2] = cvt2(st4[i*2+1][0], st4[i*2+1][1]);
        u.w[3] = cvt2(st4[i*2+1][2], st4[i*2+1][3]);
        *(s16x8*)&kbuf[b][(krow*64 + kseg + i*8) ^ sw(krow)] = u.v;
      }
    }
  };

  stage_load(0);
  stage_store(0);
  __syncthreads();
  int cur = 0;

#pragma unroll 1
  for (int kv = 0; kv < NT; ++kv){
    if (kv + 1 < NT) stage_load(kv + 1);   // async prefetch: overlaps with compute

    const float kbf = (float)(kv * KVBLK);
    const ushort* kb_ = kbuf[cur];
    const ushort* vb_ = vbuf[cur];

    // ---- K fragments (A-operand): lane ln = key, k = dh*32+lg*8+j ----
    s16x8 kf[4][2];
#pragma unroll
    for (int kt = 0; kt < 4; ++kt){
      const int key = kt*16 + ln;
      const int sz  = sw(key);
      kf[kt][0] = *(const s16x8*)&kb_[(key*64 +      lg*8) ^ sz];
      kf[kt][1] = *(const s16x8*)&kb_[(key*64 + 32 + lg*8) ^ sz];
    }

    // ---- S^T = K · Q^T : C[row=key(lg*4+r)][col=q(ln)] ----
    f32x4 S[2][4];
#pragma unroll
    for (int rg = 0; rg < 2; ++rg)
#pragma unroll
      for (int kt = 0; kt < 4; ++kt){
        f32x4 c = (f32x4)(0.0f);
        c = __builtin_amdgcn_mfma_f32_16x16x32_bf16(kf[kt][0], qf[rg][0], c, 0, 0, 0);
        c = __builtin_amdgcn_mfma_f32_16x16x32_bf16(kf[kt][1], qf[rg][1], c, 0, 0, 0);
        S[rg][kt] = c;
      }

    // ---- bias + online softmax (per lane: one q-row per rg, 16 scores) ----
    s16x4 pb[2][4];
#pragma unroll
    for (int rg = 0; rg < 2; ++rg){
      const float base = qposf[rg] - kbf - koffb;   // dist = |base - (kt*16+r)|
#pragma unroll
      for (int kt = 0; kt < 4; ++kt)
#pragma unroll
        for (int r = 0; r < 4; ++r)
          S[rg][kt][r] = fmaf(-bs, fabsf(base - (float)(kt*16 + r)), S[rg][kt][r]);

      float a0 = fmaxf(fmaxf(S[rg][0][0], S[rg][0][1]), fmaxf(S[rg][0][2], S[rg][0][3]));
      float a1 = fmaxf(fmaxf(S[rg][1][0], S[rg][1][1]), fmaxf(S[rg][1][2], S[rg][1][3]));
      float a2 = fmaxf(fmaxf(S[rg][2][0], S[rg][2][1]), fmaxf(S[rg][2][2], S[rg][2][3]));
      float a3 = fmaxf(fmaxf(S[rg][3][0], S[rg][3][1]), fmaxf(S[rg][3][2], S[rg][3][3]));
      float mx = fmaxf(fmaxf(a0, a1), fmaxf(a2, a3));
      mx = fmaxf(mx, __shfl_xor(mx, 16, 64));
      mx = fmaxf(mx, __shfl_xor(mx, 32, 64));

      const float mo = mreg[rg];
      const float mn = fmaxf(mo, mx);
      const float sc = exp2f(mo - mn);
      mreg[rg] = mn;

      float p[16];
#pragma unroll
      for (int kt = 0; kt < 4; ++kt)
#pragma unroll
        for (int r = 0; r < 4; ++r)
          p[kt*4 + r] = exp2f(S[rg][kt][r] - mn);

      float s0 = (p[0]+p[1]) + (p[2]+p[3]);
      float s1 = (p[4]+p[5]) + (p[6]+p[7]);
      float s2 = (p[8]+p[9]) + (p[10]+p[11]);
      float s3 = (p[12]+p[13]) + (p[14]+p[15]);
      float sum = (s0+s1) + (s2+s3);
      sum += __shfl_xor(sum, 16, 64);
      sum += __shfl_xor(sum, 32, 64);
      lreg[rg] = lreg[rg] * sc + sum;

#pragma unroll
      for (int dt = 0; dt < 4; ++dt) acc[rg][dt] *= sc;

#pragma unroll
      for (int kt = 0; kt < 4; ++kt){
        union { uint32_t w[2]; s16x4 v; } u;
        u.w[0] = cvt2(p[kt*4+0], p[kt*4+1]);
        u.w[1] = cvt2(p[kt*4+2], p[kt*4+3]);
        pb[rg][kt] = u.v;
      }
    }

    // ---- O^T += V^T · P^T : A = V^T[d][k] from vbuf, B = pb (in-register) ----
#pragma unroll
    for (int dt = 0; dt < 4; ++dt){
      const int d  = dt*16 + ln;
      const int sz = sw(d);
#pragma unroll
      for (int kt = 0; kt < 4; ++kt){
        const s16x4 vf = *(const s16x4*)&vb_[(d*64 + kt*16 + lg*4) ^ sz];
        acc[0][dt] = __builtin_amdgcn_mfma_f32_16x16x16bf16_1k(vf, pb[0][kt], acc[0][dt], 0, 0, 0);
        acc[1][dt] = __builtin_amdgcn_mfma_f32_16x16x16bf16_1k(vf, pb[1][kt], acc[1][dt], 0, 0, 0);
      }
    }

    if (kv + 1 < NT){
      stage_store(cur ^ 1);   // waits vmcnt via register deps, writes other buffer
      __syncthreads();        // publish + retire reads of buf[cur]
      cur ^= 1;
    }
  }

  // ---- epilogue: O[q][d] ; lane holds d = dt*16 + lg*4 + r for q = qb+rg*16+ln ----
#pragma unroll
  for (int rg = 0; rg < 2; ++rg){
    const float inv = 1.0f / lreg[rg];
    float* op = Og + headoff + (size_t)(qb + rg*16 + ln) * DHEAD + lg*4;
#pragma unroll
    for (int dt = 0; dt < 4; ++dt){
      f4 o;
      o[0] = acc[rg][dt][0] * inv;
      o[1] = acc[rg][dt][1] * inv;
      o[2] = acc[rg][dt][2] * inv;
      o[3] = acc[rg][dt][3] * inv;
      *(f4*)(op + dt*16) = o;
    }
  }
}

extern "C" void kernel_launch(void* const* d_in, const int* in_sizes, int n_in,
                              void* d_out, int out_size, void* d_ws, size_t ws_size,
                              hipStream_t stream)
{
  const float* Q = (const float*)d_in[0];
  const float* K = (const float*)d_in[1];
  const float* V = (const float*)d_in[2];
  float* O = (float*)d_out;
  dim3 grid(T_LEN / QBLK * NHEAD);   // 512 blocks
  dim3 block(256);
  hipLaunchKernelGGL(alibi_attn_kernel, grid, block, 0, stream, Q, K, V, O);
}

// Round 5
// 191.621 us; speedup vs baseline: 5.7244x; 1.1074x over previous
//
#include <hip/hip_runtime.h>
#include <hip/hip_bf16.h>
#include <stdint.h>

typedef float f4    __attribute__((ext_vector_type(4)));
typedef float f32x4 __attribute__((ext_vector_type(4)));
typedef short s16x8 __attribute__((ext_vector_type(8)));
typedef short s16x4 __attribute__((ext_vector_type(4)));

#define T_LEN 4096
#define NHEAD 16
#define DHEAD 64
#define QBLK  128
#define KVBLK 64
#define NT    (T_LEN / KVBLK)

// bf16 pack of a pair in 3 VALU: round-half-up then v_perm_b32 byte-select.
// D = {bf16(b) : bf16(a)}  (a -> low 16, b -> high 16)
__device__ __forceinline__ uint32_t pk2(float a, float b){
  uint32_t ua = __builtin_bit_cast(uint32_t, a) + 0x8000u;
  uint32_t ub = __builtin_bit_cast(uint32_t, b) + 0x8000u;
  return __builtin_amdgcn_perm(ub, ua, 0x07060302u);
}
__device__ __forceinline__ int sw(int r){ return ((r ^ (r >> 3)) & 7) << 3; }

__global__ __launch_bounds__(256, 2)
void alibi_attn_kernel(const float* __restrict__ Qg,
                       const float* __restrict__ Kg,
                       const float* __restrict__ Vg,
                       float* __restrict__ Og)
{
  __shared__ ushort kbuf[2][KVBLK * DHEAD];   // [key][d] bf16, swizzled
  __shared__ ushort vbuf[2][DHEAD * KVBLK];   // [d][key] bf16, swizzled

  // XCD-aware bijective swizzle: 512 blocks, 8 XCDs -> 2 heads per XCD
  const int bid = blockIdx.x;
  const int fid = (bid & 7) * 64 + (bid >> 3);
  const int h  = fid >> 5;
  const int qt = fid & 31;

  const int tid  = threadIdx.x;
  const int wave = tid >> 6;
  const int lane = tid & 63;
  const int lg   = lane >> 4;
  const int ln   = lane & 15;

  const int qb = qt * QBLK + wave * 32;
  const float slope = exp2f(-0.5f * (float)(h + 1));
  const float cs = 0.125f * 1.44269504089f;    // 1/sqrt(64)*log2(e), folded into Q
  const float bs = slope * 1.44269504089f;
  const size_t headoff = (size_t)h * T_LEN * DHEAD;

  // ---- Q fragments (B-operand of swapped QK^T): lane ln = q, k = dh*32+lg*8+j ----
  s16x8 qf[2][2];
#pragma unroll
  for (int rg = 0; rg < 2; ++rg)
#pragma unroll
    for (int dh = 0; dh < 2; ++dh){
      const float* qp = Qg + headoff + (size_t)(qb + rg*16 + ln) * DHEAD + dh*32 + lg*8;
      f4 x = *(const f4*)qp;
      f4 y = *(const f4*)(qp + 4);
      union { uint32_t w[4]; s16x8 v; } u;
      u.w[0] = pk2(x[0]*cs, x[1]*cs);
      u.w[1] = pk2(x[2]*cs, x[3]*cs);
      u.w[2] = pk2(y[0]*cs, y[1]*cs);
      u.w[3] = pk2(y[2]*cs, y[3]*cs);
      qf[rg][dh] = u.v;
    }

  f32x4 acc[2][4];
#pragma unroll
  for (int rg = 0; rg < 2; ++rg)
#pragma unroll
    for (int dt = 0; dt < 4; ++dt) acc[rg][dt] = (f32x4)(0.0f);
  float mreg[2] = {-1e30f, -1e30f};
  float lreg[2] = {0.0f, 0.0f};
  const float qposf[2] = {(float)(qb + ln), (float)(qb + 16 + ln)};
  const float koffb = (float)(lg * 4);

  // staging: waves 0,1 (tid<128) handle V; waves 2,3 handle K
  f4 st4[8];
  const int vk0  = (tid >> 2) * 2;         // key pair base (V threads)
  const int vseg = (tid & 3) * 16;         // d segment     (V threads)
  const int krow = (tid - 128) >> 1;       // key row       (K threads)
  const int kseg = ((tid - 128) & 1) * 32; // d segment     (K threads)
  const float* Vb = Vg + headoff;
  const float* Kb = Kg + headoff;

  auto stage_load = [&](int kv){
    const int kb = kv * KVBLK;
    if (tid < 128){
      const float* vp = Vb + (size_t)(kb + vk0) * DHEAD + vseg;
      st4[0] = *(const f4*)(vp);      st4[1] = *(const f4*)(vp + 4);
      st4[2] = *(const f4*)(vp + 8);  st4[3] = *(const f4*)(vp + 12);
      st4[4] = *(const f4*)(vp + 64); st4[5] = *(const f4*)(vp + 68);
      st4[6] = *(const f4*)(vp + 72); st4[7] = *(const f4*)(vp + 76);
    } else {
      const float* kp = Kb + (size_t)(kb + krow) * DHEAD + kseg;
#pragma unroll
      for (int j = 0; j < 8; ++j) st4[j] = *(const f4*)(kp + j*4);
    }
  };
  auto stage_store = [&](int b){
    if (tid < 128){
#pragma unroll
      for (int i = 0; i < 16; ++i){
        const int d = vseg + i;
        uint32_t pr = pk2(st4[i>>2][i&3], st4[4 + (i>>2)][i&3]);
        *(uint32_t*)&vbuf[b][(d*64 + vk0) ^ sw(d)] = pr;
      }
    } else {
#pragma unroll
      for (int i = 0; i < 4; ++i){
        union { uint32_t w[4]; s16x8 v; } u;
        u.w[0] = pk2(st4[i*2][0],   st4[i*2][1]);
        u.w[1] = pk2(st4[i*2][2],   st4[i*2][3]);
        u.w[2] = pk2(st4[i*2+1][0], st4[i*2+1][1]);
        u.w[3] = pk2(st4[i*2+1][2], st4[i*2+1][3]);
        *(s16x8*)&kbuf[b][(krow*64 + kseg + i*8) ^ sw(krow)] = u.v;
      }
    }
  };

  stage_load(0);
  stage_store(0);
  __syncthreads();
  int cur = 0;

#pragma unroll 1
  for (int kv = 0; kv < NT; ++kv){
    if (kv + 1 < NT) stage_load(kv + 1);   // async prefetch: overlaps with compute

    const float kbf = (float)(kv * KVBLK);
    const ushort* kb_ = kbuf[cur];
    const ushort* vb_ = vbuf[cur];

    // ---- K fragments (A-operand): lane ln = key, k = dh*32+lg*8+j ----
    s16x8 kf[4][2];
#pragma unroll
    for (int kt = 0; kt < 4; ++kt){
      const int key = kt*16 + ln;
      const int sz  = sw(key);
      kf[kt][0] = *(const s16x8*)&kb_[(key*64 +      lg*8) ^ sz];
      kf[kt][1] = *(const s16x8*)&kb_[(key*64 + 32 + lg*8) ^ sz];
    }

    // ---- S^T = K · Q^T : C[row=key(lg*4+r)][col=q(ln)] ----
    f32x4 S[2][4];
#pragma unroll
    for (int rg = 0; rg < 2; ++rg)
#pragma unroll
      for (int kt = 0; kt < 4; ++kt){
        f32x4 c = (f32x4)(0.0f);
        c = __builtin_amdgcn_mfma_f32_16x16x32_bf16(kf[kt][0], qf[rg][0], c, 0, 0, 0);
        c = __builtin_amdgcn_mfma_f32_16x16x32_bf16(kf[kt][1], qf[rg][1], c, 0, 0, 0);
        S[rg][kt] = c;
      }

    // ---- bias + online softmax (per lane: one q-row per rg, 16 scores) ----
    s16x4 pb[2][4];
#pragma unroll
    for (int rg = 0; rg < 2; ++rg){
      const float base = qposf[rg] - kbf - koffb;   // dist = |base - (kt*16+r)|
#pragma unroll
      for (int kt = 0; kt < 4; ++kt)
#pragma unroll
        for (int r = 0; r < 4; ++r)
          S[rg][kt][r] = fmaf(-bs, fabsf(base - (float)(kt*16 + r)), S[rg][kt][r]);

      float a0 = fmaxf(fmaxf(S[rg][0][0], S[rg][0][1]), fmaxf(S[rg][0][2], S[rg][0][3]));
      float a1 = fmaxf(fmaxf(S[rg][1][0], S[rg][1][1]), fmaxf(S[rg][1][2], S[rg][1][3]));
      float a2 = fmaxf(fmaxf(S[rg][2][0], S[rg][2][1]), fmaxf(S[rg][2][2], S[rg][2][3]));
      float a3 = fmaxf(fmaxf(S[rg][3][0], S[rg][3][1]), fmaxf(S[rg][3][2], S[rg][3][3]));
      float mx = fmaxf(fmaxf(a0, a1), fmaxf(a2, a3));
      mx = fmaxf(mx, __shfl_xor(mx, 16, 64));
      mx = fmaxf(mx, __shfl_xor(mx, 32, 64));

      const float mo = mreg[rg];
      const float mn = fmaxf(mo, mx);
      const float sc = exp2f(mo - mn);
      mreg[rg] = mn;

      float p[16];
#pragma unroll
      for (int kt = 0; kt < 4; ++kt)
#pragma unroll
        for (int r = 0; r < 4; ++r)
          p[kt*4 + r] = exp2f(S[rg][kt][r] - mn);

      float s0 = (p[0]+p[1]) + (p[2]+p[3]);
      float s1 = (p[4]+p[5]) + (p[6]+p[7]);
      float s2 = (p[8]+p[9]) + (p[10]+p[11]);
      float s3 = (p[12]+p[13]) + (p[14]+p[15]);
      float sum = (s0+s1) + (s2+s3);
      sum += __shfl_xor(sum, 16, 64);
      sum += __shfl_xor(sum, 32, 64);
      lreg[rg] = lreg[rg] * sc + sum;

#pragma unroll
      for (int dt = 0; dt < 4; ++dt) acc[rg][dt] *= sc;

#pragma unroll
      for (int kt = 0; kt < 4; ++kt){
        union { uint32_t w[2]; s16x4 v; } u;
        u.w[0] = pk2(p[kt*4+0], p[kt*4+1]);
        u.w[1] = pk2(p[kt*4+2], p[kt*4+3]);
        pb[rg][kt] = u.v;
      }
    }

    // ---- O^T += V^T · P^T : A = V^T[d][k] from vbuf, B = pb (in-register) ----
#pragma unroll
    for (int dt = 0; dt < 4; ++dt){
      const int d  = dt*16 + ln;
      const int sz = sw(d);
#pragma unroll
      for (int kt = 0; kt < 4; ++kt){
        const s16x4 vf = *(const s16x4*)&vb_[(d*64 + kt*16 + lg*4) ^ sz];
        acc[0][dt] = __builtin_amdgcn_mfma_f32_16x16x16bf16_1k(vf, pb[0][kt], acc[0][dt], 0, 0, 0);
        acc[1][dt] = __builtin_amdgcn_mfma_f32_16x16x16bf16_1k(vf, pb[1][kt], acc[1][dt], 0, 0, 0);
      }
    }

    if (kv + 1 < NT){
      stage_store(cur ^ 1);   // waits vmcnt via register deps, writes other buffer
      __syncthreads();        // publish + retire reads of buf[cur]
      cur ^= 1;
    }
  }

  // ---- epilogue: O[q][d] ; lane holds d = dt*16 + lg*4 + r for q = qb+rg*16+ln ----
#pragma unroll
  for (int rg = 0; rg < 2; ++rg){
    const float inv = 1.0f / lreg[rg];
    float* op = Og + headoff + (size_t)(qb + rg*16 + ln) * DHEAD + lg*4;
#pragma unroll
    for (int dt = 0; dt < 4; ++dt){
      f4 o;
      o[0] = acc[rg][dt][0] * inv;
      o[1] = acc[rg][dt][1] * inv;
      o[2] = acc[rg][dt][2] * inv;
      o[3] = acc[rg][dt][3] * inv;
      *(f4*)(op + dt*16) = o;
    }
  }
}

extern "C" void kernel_launch(void* const* d_in, const int* in_sizes, int n_in,
                              void* d_out, int out_size, void* d_ws, size_t ws_size,
                              hipStream_t stream)
{
  const float* Q = (const float*)d_in[0];
  const float* K = (const float*)d_in[1];
  const float* V = (const float*)d_in[2];
  float* O = (float*)d_out;
  dim3 grid(T_LEN / QBLK * NHEAD);   // 512 blocks
  dim3 block(256);
  hipLaunchKernelGGL(alibi_attn_kernel, grid, block, 0, stream, Q, K, V, O);
}

// Round 6
// 154.865 us; speedup vs baseline: 7.0830x; 1.2373x over previous
//
#include <hip/hip_runtime.h>
#include <hip/hip_bf16.h>
#include <stdint.h>

typedef float f4    __attribute__((ext_vector_type(4)));
typedef float f32x4 __attribute__((ext_vector_type(4)));
typedef short s16x8 __attribute__((ext_vector_type(8)));
typedef short s16x4 __attribute__((ext_vector_type(4)));
typedef unsigned short u16;

#define T_LEN 4096
#define NHEAD 16
#define DHEAD 64
#define KVBLK 64
#define NT    (T_LEN / KVBLK)

#if __has_builtin(__builtin_amdgcn_exp2f)
#define EXP2(x) __builtin_amdgcn_exp2f(x)
#else
#define EXP2(x) exp2f(x)
#endif

// bf16 pack of a pair in 3 VALU: round-half-up then v_perm_b32 byte-select.
__device__ __forceinline__ uint32_t pk2(float a, float b){
  uint32_t ua = __builtin_bit_cast(uint32_t, a) + 0x8000u;
  uint32_t ub = __builtin_bit_cast(uint32_t, b) + 0x8000u;
  return __builtin_amdgcn_perm(ub, ua, 0x07060302u);
}
__device__ __forceinline__ int swk(int r){ return (r ^ (r >> 3)) & 7; }   // group swizzle
__device__ __forceinline__ int sw(int r){ return swk(r) << 3; }           // ushort-idx form

// ---------------- pre-pass: K fp32 -> bf16 (same layout) ----------------
__global__ __launch_bounds__(256)
void cvt_k(const float* __restrict__ K, u16* __restrict__ Kb){
  const size_t i = ((size_t)blockIdx.x * 256 + threadIdx.x) * 8;
  f4 a = *(const f4*)(K + i);
  f4 b = *(const f4*)(K + i + 4);
  union { uint32_t w[4]; s16x8 v; } u;
  u.w[0] = pk2(a[0], a[1]); u.w[1] = pk2(a[2], a[3]);
  u.w[2] = pk2(b[0], b[1]); u.w[3] = pk2(b[2], b[3]);
  *(s16x8*)(Kb + i) = u.v;
}

// ---------------- pre-pass: V fp32 [h][t][d] -> bf16 V^T [h][d][t] ----------------
__global__ __launch_bounds__(256)
void cvt_vt(const float* __restrict__ V, u16* __restrict__ VT){
  __shared__ u16 tile[64][66];
  const int h  = blockIdx.x >> 6;
  const int kt = blockIdx.x & 63;
  const int t  = threadIdx.x;
  const float* Vh = V + ((size_t)h * T_LEN + kt * 64) * DHEAD;

  const int r = t >> 2, c = (t & 3) * 16;
  f4 x0 = *(const f4*)(Vh + r*64 + c);
  f4 x1 = *(const f4*)(Vh + r*64 + c + 4);
  f4 x2 = *(const f4*)(Vh + r*64 + c + 8);
  f4 x3 = *(const f4*)(Vh + r*64 + c + 12);
  uint32_t* tp = (uint32_t*)&tile[r][c];
  tp[0] = pk2(x0[0],x0[1]); tp[1] = pk2(x0[2],x0[3]);
  tp[2] = pk2(x1[0],x1[1]); tp[3] = pk2(x1[2],x1[3]);
  tp[4] = pk2(x2[0],x2[1]); tp[5] = pk2(x2[2],x2[3]);
  tp[6] = pk2(x3[0],x3[1]); tp[7] = pk2(x3[2],x3[3]);
  __syncthreads();

  const int d = t >> 2, ks = (t & 3) * 16;
  u16* op = VT + ((size_t)h * DHEAD + d) * T_LEN + kt * 64 + ks;
  union { uint32_t w[4]; s16x8 v; } o0, o1;
#pragma unroll
  for (int q = 0; q < 4; ++q)
    o0.w[q] = (uint32_t)tile[ks + 2*q][d]     | ((uint32_t)tile[ks + 2*q + 1][d] << 16);
#pragma unroll
  for (int q = 0; q < 4; ++q)
    o1.w[q] = (uint32_t)tile[ks + 8 + 2*q][d] | ((uint32_t)tile[ks + 9 + 2*q][d] << 16);
  *(s16x8*)(op)     = o0.v;
  *(s16x8*)(op + 8) = o1.v;
}

// ---------------- main attention: QBLK=64, 4 blocks/CU ----------------
__global__ __launch_bounds__(256, 4)
void alibi_attn2(const float* __restrict__ Qg,
                 const u16* __restrict__ Kb,
                 const u16* __restrict__ VTb,
                 float* __restrict__ Og)
{
  __shared__ u16 kbuf[2][KVBLK * DHEAD];   // [key][d] bf16, swizzled groups
  __shared__ u16 vbuf[2][DHEAD * KVBLK];   // [d][key] bf16, swizzled groups

  // XCD-aware bijective swizzle: 1024 blocks, 8 XCDs -> 2 heads per XCD
  const int bid = blockIdx.x;
  const int fid = (bid & 7) * 128 + (bid >> 3);
  const int h  = fid >> 6;
  const int qt = fid & 63;

  const int tid  = threadIdx.x;
  const int w    = tid >> 6;
  const int lane = tid & 63;
  const int lg   = lane >> 4;
  const int ln   = lane & 15;

  const int qrow = qt * 64 + w * 16 + ln;      // this lane's q-row
  const float slope = exp2f(-0.5f * (float)(h + 1));
  const float cs = 0.125f * 1.44269504089f;    // 1/sqrt(64)*log2(e), folded into Q
  const float bs = slope * 1.44269504089f;
  const size_t headoff = (size_t)h * T_LEN * DHEAD;

  // ---- Q fragments (B-operand of swapped QK^T): lane ln = q, k = dh*32+lg*8+j ----
  s16x8 qf0, qf1;
  {
    const float* qp = Qg + headoff + (size_t)qrow * DHEAD + lg * 8;
    f4 x = *(const f4*)qp;       f4 y = *(const f4*)(qp + 4);
    f4 z = *(const f4*)(qp + 32); f4 v = *(const f4*)(qp + 36);
    union { uint32_t w_[4]; s16x8 v_; } u0, u1;
    u0.w_[0] = pk2(x[0]*cs, x[1]*cs); u0.w_[1] = pk2(x[2]*cs, x[3]*cs);
    u0.w_[2] = pk2(y[0]*cs, y[1]*cs); u0.w_[3] = pk2(y[2]*cs, y[3]*cs);
    u1.w_[0] = pk2(z[0]*cs, z[1]*cs); u1.w_[1] = pk2(z[2]*cs, z[3]*cs);
    u1.w_[2] = pk2(v[0]*cs, v[1]*cs); u1.w_[3] = pk2(v[2]*cs, v[3]*cs);
    qf0 = u0.v_; qf1 = u1.v_;
  }

  f32x4 acc[4];
#pragma unroll
  for (int dt = 0; dt < 4; ++dt) acc[dt] = (f32x4)(0.0f);
  float m = -1e30f, l = 0.0f;
  const float qposf = (float)qrow;
  const float koffb = (float)(lg * 4);

  // ---- staging precompute: linear LDS dest (lane*16B), inverse-swizzled source ----
  const u16* Kh = Kb  + headoff;
  const u16* Vh = VTb + headoff;
  const int sA = w * 128 + lane;     // slot for j=0
  const int sB = sA + 64;            // slot for j=1
  const int keyA = sA >> 3, gA = (sA & 7) ^ swk(keyA);
  const int keyB = sB >> 3, gB = (sB & 7) ^ swk(keyB);
  const int vdA  = sA >> 3, vgA = (sA & 7) ^ swk(vdA);
  const int vdB  = sB >> 3, vgB = (sB & 7) ^ swk(vdB);
  const u16* kpA = Kh + keyA * 64 + gA * 8;
  const u16* kpB = Kh + keyB * 64 + gB * 8;
  const u16* vpA = Vh + (size_t)vdA * T_LEN + vgA * 8;
  const u16* vpB = Vh + (size_t)vdB * T_LEN + vgB * 8;
  const int dstA = sA * 8, dstB = sB * 8;   // ushort index, linear

  s16x8 rkA, rkB, rvA, rvB;
  auto ldregs = [&](){
    rkA = *(const s16x8*)kpA;  rkB = *(const s16x8*)kpB;
    rvA = *(const s16x8*)vpA;  rvB = *(const s16x8*)vpB;
    kpA += KVBLK * DHEAD; kpB += KVBLK * DHEAD;   // next K tile (4096 elems)
    vpA += KVBLK;         vpB += KVBLK;           // next V^T tile (64 elems)
  };
  auto wrregs = [&](int b){
    *(s16x8*)&kbuf[b][dstA] = rkA;  *(s16x8*)&kbuf[b][dstB] = rkB;
    *(s16x8*)&vbuf[b][dstA] = rvA;  *(s16x8*)&vbuf[b][dstB] = rvB;
  };

  ldregs();
  wrregs(0);
  __syncthreads();
  int cur = 0;

#pragma unroll 1
  for (int kv = 0; kv < NT; ++kv){
    if (kv + 1 < NT) ldregs();      // issue next-tile loads early (T14)

    const float kbf = (float)(kv * KVBLK);
    const u16* kb_ = kbuf[cur];
    const u16* vb_ = vbuf[cur];

    // ---- S^T = K · Q^T : per kt, load kf + 2 MFMA ----
    f32x4 S[4];
#pragma unroll
    for (int kt = 0; kt < 4; ++kt){
      const int key = kt * 16 + ln;
      const int sz  = sw(key);
      s16x8 k0 = *(const s16x8*)&kb_[(key*64 +      lg*8) ^ sz];
      s16x8 k1 = *(const s16x8*)&kb_[(key*64 + 32 + lg*8) ^ sz];
      f32x4 c = (f32x4)(0.0f);
      c = __builtin_amdgcn_mfma_f32_16x16x32_bf16(k0, qf0, c, 0, 0, 0);
      c = __builtin_amdgcn_mfma_f32_16x16x32_bf16(k1, qf1, c, 0, 0, 0);
      S[kt] = c;
    }

    // ---- bias + online softmax (1 q-row per lane, 16 scores) ----
    const float base = qposf - kbf - koffb;
#pragma unroll
    for (int kt = 0; kt < 4; ++kt)
#pragma unroll
      for (int r = 0; r < 4; ++r)
        S[kt][r] = fmaf(-bs, fabsf(base - (float)(kt*16 + r)), S[kt][r]);

    float a0 = fmaxf(fmaxf(S[0][0], S[0][1]), fmaxf(S[0][2], S[0][3]));
    float a1 = fmaxf(fmaxf(S[1][0], S[1][1]), fmaxf(S[1][2], S[1][3]));
    float a2 = fmaxf(fmaxf(S[2][0], S[2][1]), fmaxf(S[2][2], S[2][3]));
    float a3 = fmaxf(fmaxf(S[3][0], S[3][1]), fmaxf(S[3][2], S[3][3]));
    float mx = fmaxf(fmaxf(a0, a1), fmaxf(a2, a3));
    mx = fmaxf(mx, __shfl_xor(mx, 16, 64));
    mx = fmaxf(mx, __shfl_xor(mx, 32, 64));

    const float mo = m;
    const float mn = fmaxf(mo, mx);
    const float scl = EXP2(mo - mn);
    m = mn;

#pragma unroll
    for (int kt = 0; kt < 4; ++kt)
#pragma unroll
      for (int r = 0; r < 4; ++r)
        S[kt][r] = EXP2(S[kt][r] - mn);

    float s0 = (S[0][0]+S[0][1]) + (S[0][2]+S[0][3]);
    float s1 = (S[1][0]+S[1][1]) + (S[1][2]+S[1][3]);
    float s2 = (S[2][0]+S[2][1]) + (S[2][2]+S[2][3]);
    float s3 = (S[3][0]+S[3][1]) + (S[3][2]+S[3][3]);
    float sum = (s0+s1) + (s2+s3);
    sum += __shfl_xor(sum, 16, 64);
    sum += __shfl_xor(sum, 32, 64);
    l = l * scl + sum;

#pragma unroll
    for (int dt = 0; dt < 4; ++dt) acc[dt] *= scl;

    s16x4 pb[4];
#pragma unroll
    for (int kt = 0; kt < 4; ++kt){
      union { uint32_t w_[2]; s16x4 v_; } u;
      u.w_[0] = pk2(S[kt][0], S[kt][1]);
      u.w_[1] = pk2(S[kt][2], S[kt][3]);
      pb[kt] = u.v_;
    }

    // ---- O^T += V^T · P^T ----
#pragma unroll
    for (int dt = 0; dt < 4; ++dt){
      const int d  = dt*16 + ln;
      const int sz = sw(d);
#pragma unroll
      for (int kt = 0; kt < 4; ++kt){
        const s16x4 vf = *(const s16x4*)&vb_[(d*64 + kt*16 + lg*4) ^ sz];
        acc[dt] = __builtin_amdgcn_mfma_f32_16x16x16bf16_1k(vf, pb[kt], acc[dt], 0, 0, 0);
      }
    }

    if (kv + 1 < NT){
      wrregs(cur ^ 1);      // regs landed during compute; write other buffer
      __syncthreads();
      cur ^= 1;
    }
  }

  // ---- epilogue ----
  const float inv = 1.0f / l;
  float* op = Og + headoff + (size_t)qrow * DHEAD + lg * 4;
#pragma unroll
  for (int dt = 0; dt < 4; ++dt){
    f4 o;
    o[0] = acc[dt][0] * inv; o[1] = acc[dt][1] * inv;
    o[2] = acc[dt][2] * inv; o[3] = acc[dt][3] * inv;
    *(f4*)(op + dt*16) = o;
  }
}

// ---------------- fallback (round-5 kernel, used when ws too small) ----------------
__global__ __launch_bounds__(256, 2)
void alibi_attn_fb(const float* __restrict__ Qg,
                   const float* __restrict__ Kg,
                   const float* __restrict__ Vg,
                   float* __restrict__ Og)
{
  __shared__ u16 kbuf[2][KVBLK * DHEAD];
  __shared__ u16 vbuf[2][DHEAD * KVBLK];

  const int bid = blockIdx.x;
  const int fid = (bid & 7) * 64 + (bid >> 3);
  const int h  = fid >> 5;
  const int qt = fid & 31;

  const int tid  = threadIdx.x;
  const int wave = tid >> 6;
  const int lane = tid & 63;
  const int lg   = lane >> 4;
  const int ln   = lane & 15;

  const int qb = qt * 128 + wave * 32;
  const float slope = exp2f(-0.5f * (float)(h + 1));
  const float cs = 0.125f * 1.44269504089f;
  const float bs = slope * 1.44269504089f;
  const size_t headoff = (size_t)h * T_LEN * DHEAD;

  s16x8 qf[2][2];
#pragma unroll
  for (int rg = 0; rg < 2; ++rg)
#pragma unroll
    for (int dh = 0; dh < 2; ++dh){
      const float* qp = Qg + headoff + (size_t)(qb + rg*16 + ln) * DHEAD + dh*32 + lg*8;
      f4 x = *(const f4*)qp;
      f4 y = *(const f4*)(qp + 4);
      union { uint32_t w[4]; s16x8 v; } u;
      u.w[0] = pk2(x[0]*cs, x[1]*cs);
      u.w[1] = pk2(x[2]*cs, x[3]*cs);
      u.w[2] = pk2(y[0]*cs, y[1]*cs);
      u.w[3] = pk2(y[2]*cs, y[3]*cs);
      qf[rg][dh] = u.v;
    }

  f32x4 acc[2][4];
#pragma unroll
  for (int rg = 0; rg < 2; ++rg)
#pragma unroll
    for (int dt = 0; dt < 4; ++dt) acc[rg][dt] = (f32x4)(0.0f);
  float mreg[2] = {-1e30f, -1e30f};
  float lreg[2] = {0.0f, 0.0f};
  const float qposf[2] = {(float)(qb + ln), (float)(qb + 16 + ln)};
  const float koffb = (float)(lg * 4);

  f4 st4[8];
  const int vk0  = (tid >> 2) * 2;
  const int vseg = (tid & 3) * 16;
  const int krow = (tid - 128) >> 1;
  const int kseg = ((tid - 128) & 1) * 32;
  const float* Vb = Vg + headoff;
  const float* Kb_ = Kg + headoff;

  auto stage_load = [&](int kv){
    const int kb = kv * KVBLK;
    if (tid < 128){
      const float* vp = Vb + (size_t)(kb + vk0) * DHEAD + vseg;
      st4[0] = *(const f4*)(vp);      st4[1] = *(const f4*)(vp + 4);
      st4[2] = *(const f4*)(vp + 8);  st4[3] = *(const f4*)(vp + 12);
      st4[4] = *(const f4*)(vp + 64); st4[5] = *(const f4*)(vp + 68);
      st4[6] = *(const f4*)(vp + 72); st4[7] = *(const f4*)(vp + 76);
    } else {
      const float* kp = Kb_ + (size_t)(kb + krow) * DHEAD + kseg;
#pragma unroll
      for (int j = 0; j < 8; ++j) st4[j] = *(const f4*)(kp + j*4);
    }
  };
  auto stage_store = [&](int b){
    if (tid < 128){
#pragma unroll
      for (int i = 0; i < 16; ++i){
        const int d = vseg + i;
        uint32_t pr = pk2(st4[i>>2][i&3], st4[4 + (i>>2)][i&3]);
        *(uint32_t*)&vbuf[b][(d*64 + vk0) ^ sw(d)] = pr;
      }
    } else {
#pragma unroll
      for (int i = 0; i < 4; ++i){
        union { uint32_t w[4]; s16x8 v; } u;
        u.w[0] = pk2(st4[i*2][0],   st4[i*2][1]);
        u.w[1] = pk2(st4[i*2][2],   st4[i*2][3]);
        u.w[2] = pk2(st4[i*2+1][0], st4[i*2+1][1]);
        u.w[3] = pk2(st4[i*2+1][2], st4[i*2+1][3]);
        *(s16x8*)&kbuf[b][(krow*64 + kseg + i*8) ^ sw(krow)] = u.v;
      }
    }
  };

  stage_load(0);
  stage_store(0);
  __syncthreads();
  int cur = 0;

#pragma unroll 1
  for (int kv = 0; kv < NT; ++kv){
    if (kv + 1 < NT) stage_load(kv + 1);

    const float kbf = (float)(kv * KVBLK);
    const u16* kb_ = kbuf[cur];
    const u16* vb_ = vbuf[cur];

    s16x8 kf[4][2];
#pragma unroll
    for (int kt = 0; kt < 4; ++kt){
      const int key = kt*16 + ln;
      const int sz  = sw(key);
      kf[kt][0] = *(const s16x8*)&kb_[(key*64 +      lg*8) ^ sz];
      kf[kt][1] = *(const s16x8*)&kb_[(key*64 + 32 + lg*8) ^ sz];
    }
    f32x4 S[2][4];
#pragma unroll
    for (int rg = 0; rg < 2; ++rg)
#pragma unroll
      for (int kt = 0; kt < 4; ++kt){
        f32x4 c = (f32x4)(0.0f);
        c = __builtin_amdgcn_mfma_f32_16x16x32_bf16(kf[kt][0], qf[rg][0], c, 0, 0, 0);
        c = __builtin_amdgcn_mfma_f32_16x16x32_bf16(kf[kt][1], qf[rg][1], c, 0, 0, 0);
        S[rg][kt] = c;
      }

    s16x4 pb[2][4];
#pragma unroll
    for (int rg = 0; rg < 2; ++rg){
      const float base = qposf[rg] - kbf - koffb;
#pragma unroll
      for (int kt = 0; kt < 4; ++kt)
#pragma unroll
        for (int r = 0; r < 4; ++r)
          S[rg][kt][r] = fmaf(-bs, fabsf(base - (float)(kt*16 + r)), S[rg][kt][r]);

      float a0 = fmaxf(fmaxf(S[rg][0][0], S[rg][0][1]), fmaxf(S[rg][0][2], S[rg][0][3]));
      float a1 = fmaxf(fmaxf(S[rg][1][0], S[rg][1][1]), fmaxf(S[rg][1][2], S[rg][1][3]));
      float a2 = fmaxf(fmaxf(S[rg][2][0], S[rg][2][1]), fmaxf(S[rg][2][2], S[rg][2][3]));
      float a3 = fmaxf(fmaxf(S[rg][3][0], S[rg][3][1]), fmaxf(S[rg][3][2], S[rg][3][3]));
      float mx = fmaxf(fmaxf(a0, a1), fmaxf(a2, a3));
      mx = fmaxf(mx, __shfl_xor(mx, 16, 64));
      mx = fmaxf(mx, __shfl_xor(mx, 32, 64));

      const float mo = mreg[rg];
      const float mn = fmaxf(mo, mx);
      const float scl = EXP2(mo - mn);
      mreg[rg] = mn;

      float p[16];
#pragma unroll
      for (int kt = 0; kt < 4; ++kt)
#pragma unroll
        for (int r = 0; r < 4; ++r)
          p[kt*4 + r] = EXP2(S[rg][kt][r] - mn);

      float s0 = (p[0]+p[1]) + (p[2]+p[3]);
      float s1 = (p[4]+p[5]) + (p[6]+p[7]);
      float s2 = (p[8]+p[9]) + (p[10]+p[11]);
      float s3 = (p[12]+p[13]) + (p[14]+p[15]);
      float sum = (s0+s1) + (s2+s3);
      sum += __shfl_xor(sum, 16, 64);
      sum += __shfl_xor(sum, 32, 64);
      lreg[rg] = lreg[rg] * scl + sum;

#pragma unroll
      for (int dt = 0; dt < 4; ++dt) acc[rg][dt] *= scl;

#pragma unroll
      for (int kt = 0; kt < 4; ++kt){
        union { uint32_t w[2]; s16x4 v; } u;
        u.w[0] = pk2(p[kt*4+0], p[kt*4+1]);
        u.w[1] = pk2(p[kt*4+2], p[kt*4+3]);
        pb[rg][kt] = u.v;
      }
    }

#pragma unroll
    for (int dt = 0; dt < 4; ++dt){
      const int d  = dt*16 + ln;
      const int sz = sw(d);
#pragma unroll
      for (int kt = 0; kt < 4; ++kt){
        const s16x4 vf = *(const s16x4*)&vb_[(d*64 + kt*16 + lg*4) ^ sz];
        acc[0][dt] = __builtin_amdgcn_mfma_f32_16x16x16bf16_1k(vf, pb[0][kt], acc[0][dt], 0, 0, 0);
        acc[1][dt] = __builtin_amdgcn_mfma_f32_16x16x16bf16_1k(vf, pb[1][kt], acc[1][dt], 0, 0, 0);
      }
    }

    if (kv + 1 < NT){
      stage_store(cur ^ 1);
      __syncthreads();
      cur ^= 1;
    }
  }

#pragma unroll
  for (int rg = 0; rg < 2; ++rg){
    const float inv = 1.0f / lreg[rg];
    float* op = Og + headoff + (size_t)(qb + rg*16 + ln) * DHEAD + lg*4;
#pragma unroll
    for (int dt = 0; dt < 4; ++dt){
      f4 o;
      o[0] = acc[rg][dt][0] * inv;
      o[1] = acc[rg][dt][1] * inv;
      o[2] = acc[rg][dt][2] * inv;
      o[3] = acc[rg][dt][3] * inv;
      *(f4*)(op + dt*16) = o;
    }
  }
}

extern "C" void kernel_launch(void* const* d_in, const int* in_sizes, int n_in,
                              void* d_out, int out_size, void* d_ws, size_t ws_size,
                              hipStream_t stream)
{
  const float* Q = (const float*)d_in[0];
  const float* K = (const float*)d_in[1];
  const float* V = (const float*)d_in[2];
  float* O = (float*)d_out;

  const size_t need = (size_t)NHEAD * T_LEN * DHEAD * 2 * 2;  // K + V^T bf16 = 16 MB
  if (ws_size >= need){
    u16* Kb = (u16*)d_ws;
    u16* VT = Kb + (size_t)NHEAD * T_LEN * DHEAD;
    hipLaunchKernelGGL(cvt_k,  dim3(2048), dim3(256), 0, stream, K, Kb);
    hipLaunchKernelGGL(cvt_vt, dim3(1024), dim3(256), 0, stream, V, VT);
    hipLaunchKernelGGL(alibi_attn2, dim3(1024), dim3(256), 0, stream, Q, Kb, VT, O);
  } else {
    hipLaunchKernelGGL(alibi_attn_fb, dim3(512), dim3(256), 0, stream, Q, K, V, O);
  }
}

// Round 7
// 127.637 us; speedup vs baseline: 8.5940x; 1.2133x over previous
//
#include <hip/hip_runtime.h>
#include <hip/hip_bf16.h>
#include <stdint.h>

typedef float f4    __attribute__((ext_vector_type(4)));
typedef float f32x4 __attribute__((ext_vector_type(4)));
typedef short s16x8 __attribute__((ext_vector_type(8)));
typedef short s16x4 __attribute__((ext_vector_type(4)));
typedef unsigned short u16;

#define T_LEN 4096
#define NHEAD 16
#define DHEAD 64
#define KVBLK 64
#define NT    (T_LEN / KVBLK)

#if __has_builtin(__builtin_amdgcn_exp2f)
#define EXP2(x) __builtin_amdgcn_exp2f(x)
#else
#define EXP2(x) exp2f(x)
#endif

// bf16 pack of a pair in 3 VALU: round-half-up then v_perm_b32 byte-select.
__device__ __forceinline__ uint32_t pk2(float a, float b){
  uint32_t ua = __builtin_bit_cast(uint32_t, a) + 0x8000u;
  uint32_t ub = __builtin_bit_cast(uint32_t, b) + 0x8000u;
  return __builtin_amdgcn_perm(ub, ua, 0x07060302u);
}
__device__ __forceinline__ int swk(int r){ return (r ^ (r >> 3)) & 7; }
__device__ __forceinline__ int sw(int r){ return swk(r) << 3; }

// ---------------- pre-pass: K fp32 -> bf16 (same layout) ----------------
__global__ __launch_bounds__(256)
void cvt_k(const float* __restrict__ K, u16* __restrict__ Kb){
  const size_t i = ((size_t)blockIdx.x * 256 + threadIdx.x) * 8;
  f4 a = *(const f4*)(K + i);
  f4 b = *(const f4*)(K + i + 4);
  union { uint32_t w[4]; s16x8 v; } u;
  u.w[0] = pk2(a[0], a[1]); u.w[1] = pk2(a[2], a[3]);
  u.w[2] = pk2(b[0], b[1]); u.w[3] = pk2(b[2], b[3]);
  *(s16x8*)(Kb + i) = u.v;
}

// ---------------- pre-pass: V fp32 [h][t][d] -> bf16 V^T [h][d][t] ----------------
__global__ __launch_bounds__(256)
void cvt_vt(const float* __restrict__ V, u16* __restrict__ VT){
  __shared__ u16 tile[64][66];
  const int h  = blockIdx.x >> 6;
  const int kt = blockIdx.x & 63;
  const int t  = threadIdx.x;
  const float* Vh = V + ((size_t)h * T_LEN + kt * 64) * DHEAD;

  const int r = t >> 2, c = (t & 3) * 16;
  f4 x0 = *(const f4*)(Vh + r*64 + c);
  f4 x1 = *(const f4*)(Vh + r*64 + c + 4);
  f4 x2 = *(const f4*)(Vh + r*64 + c + 8);
  f4 x3 = *(const f4*)(Vh + r*64 + c + 12);
  uint32_t* tp = (uint32_t*)&tile[r][c];
  tp[0] = pk2(x0[0],x0[1]); tp[1] = pk2(x0[2],x0[3]);
  tp[2] = pk2(x1[0],x1[1]); tp[3] = pk2(x1[2],x1[3]);
  tp[4] = pk2(x2[0],x2[1]); tp[5] = pk2(x2[2],x2[3]);
  tp[6] = pk2(x3[0],x3[1]); tp[7] = pk2(x3[2],x3[3]);
  __syncthreads();

  const int d = t >> 2, ks = (t & 3) * 16;
  u16* op = VT + ((size_t)h * DHEAD + d) * T_LEN + kt * 64 + ks;
  union { uint32_t w[4]; s16x8 v; } o0, o1;
#pragma unroll
  for (int q = 0; q < 4; ++q)
    o0.w[q] = (uint32_t)tile[ks + 2*q][d]     | ((uint32_t)tile[ks + 2*q + 1][d] << 16);
#pragma unroll
  for (int q = 0; q < 4; ++q)
    o1.w[q] = (uint32_t)tile[ks + 8 + 2*q][d] | ((uint32_t)tile[ks + 9 + 2*q][d] << 16);
  *(s16x8*)(op)     = o0.v;
  *(s16x8*)(op + 8) = o1.v;
}

// ---------------- main attention ----------------
__global__ __launch_bounds__(256, 4)
void alibi_attn3(const float* __restrict__ Qg,
                 const u16* __restrict__ Kb,
                 const u16* __restrict__ VTb,
                 float* __restrict__ Og)
{
  __shared__ u16 kbuf[2][KVBLK * DHEAD];   // [key][d] bf16, swizzled groups
  __shared__ u16 vbuf[2][DHEAD * KVBLK];   // [d][key] bf16, swizzled groups

  // XCD-aware bijective swizzle: 1024 blocks, 8 XCDs
  const int bid = blockIdx.x;
  const int fid = (bid & 7) * 128 + (bid >> 3);
  const int h  = fid >> 6;
  const int qt = fid & 63;

  const int tid  = threadIdx.x;
  const int wv   = tid >> 6;
  const int lane = tid & 63;
  const int lg   = lane >> 4;
  const int ln   = lane & 15;

  const int qrow = qt * 64 + wv * 16 + ln;
  const float slope = exp2f(-0.5f * (float)(h + 1));
  const float cs = 0.125f * 1.44269504089f;
  const float bs = slope * 1.44269504089f;
  const size_t headoff = (size_t)h * T_LEN * DHEAD;

  // ---- Q fragments (B-operand of swapped QK^T) ----
  s16x8 qf0, qf1;
  {
    const float* qp = Qg + headoff + (size_t)qrow * DHEAD + lg * 8;
    f4 x = *(const f4*)qp;        f4 y = *(const f4*)(qp + 4);
    f4 z = *(const f4*)(qp + 32); f4 v = *(const f4*)(qp + 36);
    union { uint32_t w_[4]; s16x8 v_; } u0, u1;
    u0.w_[0] = pk2(x[0]*cs, x[1]*cs); u0.w_[1] = pk2(x[2]*cs, x[3]*cs);
    u0.w_[2] = pk2(y[0]*cs, y[1]*cs); u0.w_[3] = pk2(y[2]*cs, y[3]*cs);
    u1.w_[0] = pk2(z[0]*cs, z[1]*cs); u1.w_[1] = pk2(z[2]*cs, z[3]*cs);
    u1.w_[2] = pk2(v[0]*cs, v[1]*cs); u1.w_[3] = pk2(v[2]*cs, v[3]*cs);
    qf0 = u0.v_; qf1 = u1.v_;
  }

  f32x4 acc[4];
#pragma unroll
  for (int dt = 0; dt < 4; ++dt) acc[dt] = (f32x4)(0.0f);
  float lsum = 0.0f;
  const float base0 = (float)qrow - (float)(lg * 4);   // minus kv*64 per iter

  // ---- hoisted swizzled LDS read byte-offsets (loop-invariant) ----
  int koffs[4][2];
#pragma unroll
  for (int kt = 0; kt < 4; ++kt){
    const int key = kt*16 + ln, sz = sw(key);
    koffs[kt][0] = (((key*64      + lg*8) ^ sz)) * 2;
    koffs[kt][1] = (((key*64 + 32 + lg*8) ^ sz)) * 2;
  }
  int voffs[4][4];
#pragma unroll
  for (int dt = 0; dt < 4; ++dt){
    const int d = dt*16 + ln, sz = sw(d);
#pragma unroll
    for (int kt = 0; kt < 4; ++kt)
      voffs[dt][kt] = (((d*64 + kt*16 + lg*4) ^ sz)) * 2;
  }

  // ---- staging: linear LDS dest, inverse-swizzled global source ----
  const u16* Kh = Kb  + headoff;
  const u16* Vh = VTb + headoff;
  const int sA = wv * 128 + lane;
  const int sB = sA + 64;
  const int keyA = sA >> 3, gA = (sA & 7) ^ swk(keyA);
  const int keyB = sB >> 3, gB = (sB & 7) ^ swk(keyB);
  const int kidxA = keyA * 64 + gA * 8;
  const int kidxB = keyB * 64 + gB * 8;
  const int vidxA = keyA * T_LEN + gA * 8;   // vd == key index, vg == g
  const int vidxB = keyB * T_LEN + gB * 8;
  const int dstA = sA * 16, dstB = sB * 16;  // bytes, linear

  s16x8 rkA, rkB, rvA, rvB;
  auto ldregs = [&](int t){
    const u16* kp = Kh + (size_t)t * (KVBLK * DHEAD);
    const u16* vp = Vh + (size_t)t * KVBLK;
    rkA = *(const s16x8*)(kp + kidxA);  rkB = *(const s16x8*)(kp + kidxB);
    rvA = *(const s16x8*)(vp + vidxA);  rvB = *(const s16x8*)(vp + vidxB);
  };
  auto wrregs = [&](u16* kb_, u16* vb_){
    *(s16x8*)((char*)kb_ + dstA) = rkA;  *(s16x8*)((char*)kb_ + dstB) = rkB;
    *(s16x8*)((char*)vb_ + dstA) = rvA;  *(s16x8*)((char*)vb_ + dstB) = rvB;
  };

  auto compute = [&](const u16* kb_, const u16* vb_, int kv){
    // QK^T (swapped): S^T[key][q]
    f32x4 S[4];
    __builtin_amdgcn_s_setprio(1);
#pragma unroll
    for (int kt = 0; kt < 4; ++kt){
      s16x8 k0 = *(const s16x8*)((const char*)kb_ + koffs[kt][0]);
      s16x8 k1 = *(const s16x8*)((const char*)kb_ + koffs[kt][1]);
      f32x4 c = (f32x4)(0.0f);
      c = __builtin_amdgcn_mfma_f32_16x16x32_bf16(k0, qf0, c, 0, 0, 0);
      c = __builtin_amdgcn_mfma_f32_16x16x32_bf16(k1, qf1, c, 0, 0, 0);
      S[kt] = c;
    }
    __builtin_amdgcn_s_setprio(0);

    // bias + exp2 (no max tracking: softmax is shift-invariant, scores bounded)
    const float bi = base0 - (float)(kv * KVBLK);
    float p[16];
#pragma unroll
    for (int kt = 0; kt < 4; ++kt)
#pragma unroll
      for (int r = 0; r < 4; ++r)
        p[kt*4 + r] = EXP2(fmaf(-bs, fabsf(bi - (float)(kt*16 + r)), S[kt][r]));

    lsum += (((p[0]+p[1]) + (p[2]+p[3])) + ((p[4]+p[5]) + (p[6]+p[7])))
          + (((p[8]+p[9]) + (p[10]+p[11])) + ((p[12]+p[13]) + (p[14]+p[15])));

    s16x4 pb[4];
#pragma unroll
    for (int kt = 0; kt < 4; ++kt){
      union { uint32_t w_[2]; s16x4 v_; } u;
      u.w_[0] = pk2(p[kt*4+0], p[kt*4+1]);
      u.w_[1] = pk2(p[kt*4+2], p[kt*4+3]);
      pb[kt] = u.v_;
    }

    // PV: O^T += V^T · P^T
    __builtin_amdgcn_s_setprio(1);
#pragma unroll
    for (int dt = 0; dt < 4; ++dt){
#pragma unroll
      for (int kt = 0; kt < 4; ++kt){
        const s16x4 vf = *(const s16x4*)((const char*)vb_ + voffs[dt][kt]);
        acc[dt] = __builtin_amdgcn_mfma_f32_16x16x16bf16_1k(vf, pb[kt], acc[dt], 0, 0, 0);
      }
    }
    __builtin_amdgcn_s_setprio(0);
  };

  ldregs(0);
  wrregs(kbuf[0], vbuf[0]);
  __syncthreads();

#pragma unroll 1
  for (int kv = 0; kv < NT; kv += 2){
    // half A: compute tile kv from buf0; prefetch tile kv+1 into buf1
    ldregs(kv + 1);
    compute(kbuf[0], vbuf[0], kv);
    wrregs(kbuf[1], vbuf[1]);
    __syncthreads();
    // half B: compute tile kv+1 from buf1; prefetch tile kv+2 into buf0
    if (kv + 2 < NT){
      ldregs(kv + 2);
      compute(kbuf[1], vbuf[1], kv + 1);
      wrregs(kbuf[0], vbuf[0]);
      __syncthreads();
    } else {
      compute(kbuf[1], vbuf[1], kv + 1);
    }
  }

  // ---- epilogue: cross-lane l reduction once, then normalize + store ----
  lsum += __shfl_xor(lsum, 16, 64);
  lsum += __shfl_xor(lsum, 32, 64);
  const float inv = 1.0f / lsum;
  float* op = Og + headoff + (size_t)qrow * DHEAD + lg * 4;
#pragma unroll
  for (int dt = 0; dt < 4; ++dt){
    f4 o;
    o[0] = acc[dt][0] * inv; o[1] = acc[dt][1] * inv;
    o[2] = acc[dt][2] * inv; o[3] = acc[dt][3] * inv;
    *(f4*)(op + dt*16) = o;
  }
}

// ---------------- fallback (round-5 kernel, used when ws too small) ----------------
__global__ __launch_bounds__(256, 2)
void alibi_attn_fb(const float* __restrict__ Qg,
                   const float* __restrict__ Kg,
                   const float* __restrict__ Vg,
                   float* __restrict__ Og)
{
  __shared__ u16 kbuf[2][KVBLK * DHEAD];
  __shared__ u16 vbuf[2][DHEAD * KVBLK];

  const int bid = blockIdx.x;
  const int fid = (bid & 7) * 64 + (bid >> 3);
  const int h  = fid >> 5;
  const int qt = fid & 31;

  const int tid  = threadIdx.x;
  const int wave = tid >> 6;
  const int lane = tid & 63;
  const int lg   = lane >> 4;
  const int ln   = lane & 15;

  const int qb = qt * 128 + wave * 32;
  const float slope = exp2f(-0.5f * (float)(h + 1));
  const float cs = 0.125f * 1.44269504089f;
  const float bs = slope * 1.44269504089f;
  const size_t headoff = (size_t)h * T_LEN * DHEAD;

  s16x8 qf[2][2];
#pragma unroll
  for (int rg = 0; rg < 2; ++rg)
#pragma unroll
    for (int dh = 0; dh < 2; ++dh){
      const float* qp = Qg + headoff + (size_t)(qb + rg*16 + ln) * DHEAD + dh*32 + lg*8;
      f4 x = *(const f4*)qp;
      f4 y = *(const f4*)(qp + 4);
      union { uint32_t w[4]; s16x8 v; } u;
      u.w[0] = pk2(x[0]*cs, x[1]*cs);
      u.w[1] = pk2(x[2]*cs, x[3]*cs);
      u.w[2] = pk2(y[0]*cs, y[1]*cs);
      u.w[3] = pk2(y[2]*cs, y[3]*cs);
      qf[rg][dh] = u.v;
    }

  f32x4 acc[2][4];
#pragma unroll
  for (int rg = 0; rg < 2; ++rg)
#pragma unroll
    for (int dt = 0; dt < 4; ++dt) acc[rg][dt] = (f32x4)(0.0f);
  float mreg[2] = {-1e30f, -1e30f};
  float lreg[2] = {0.0f, 0.0f};
  const float qposf[2] = {(float)(qb + ln), (float)(qb + 16 + ln)};
  const float koffb = (float)(lg * 4);

  f4 st4[8];
  const int vk0  = (tid >> 2) * 2;
  const int vseg = (tid & 3) * 16;
  const int krow = (tid - 128) >> 1;
  const int kseg = ((tid - 128) & 1) * 32;
  const float* Vb = Vg + headoff;
  const float* Kb_ = Kg + headoff;

  auto stage_load = [&](int kv){
    const int kb = kv * KVBLK;
    if (tid < 128){
      const float* vp = Vb + (size_t)(kb + vk0) * DHEAD + vseg;
      st4[0] = *(const f4*)(vp);      st4[1] = *(const f4*)(vp + 4);
      st4[2] = *(const f4*)(vp + 8);  st4[3] = *(const f4*)(vp + 12);
      st4[4] = *(const f4*)(vp + 64); st4[5] = *(const f4*)(vp + 68);
      st4[6] = *(const f4*)(vp + 72); st4[7] = *(const f4*)(vp + 76);
    } else {
      const float* kp = Kb_ + (size_t)(kb + krow) * DHEAD + kseg;
#pragma unroll
      for (int j = 0; j < 8; ++j) st4[j] = *(const f4*)(kp + j*4);
    }
  };
  auto stage_store = [&](int b){
    if (tid < 128){
#pragma unroll
      for (int i = 0; i < 16; ++i){
        const int d = vseg + i;
        uint32_t pr = pk2(st4[i>>2][i&3], st4[4 + (i>>2)][i&3]);
        *(uint32_t*)&vbuf[b][(d*64 + vk0) ^ sw(d)] = pr;
      }
    } else {
#pragma unroll
      for (int i = 0; i < 4; ++i){
        union { uint32_t w[4]; s16x8 v; } u;
        u.w[0] = pk2(st4[i*2][0],   st4[i*2][1]);
        u.w[1] = pk2(st4[i*2][2],   st4[i*2][3]);
        u.w[2] = pk2(st4[i*2+1][0], st4[i*2+1][1]);
        u.w[3] = pk2(st4[i*2+1][2], st4[i*2+1][3]);
        *(s16x8*)&kbuf[b][(krow*64 + kseg + i*8) ^ sw(krow)] = u.v;
      }
    }
  };

  stage_load(0);
  stage_store(0);
  __syncthreads();
  int cur = 0;

#pragma unroll 1
  for (int kv = 0; kv < NT; ++kv){
    if (kv + 1 < NT) stage_load(kv + 1);

    const float kbf = (float)(kv * KVBLK);
    const u16* kb_ = kbuf[cur];
    const u16* vb_ = vbuf[cur];

    s16x8 kf[4][2];
#pragma unroll
    for (int kt = 0; kt < 4; ++kt){
      const int key = kt*16 + ln;
      const int sz  = sw(key);
      kf[kt][0] = *(const s16x8*)&kb_[(key*64 +      lg*8) ^ sz];
      kf[kt][1] = *(const s16x8*)&kb_[(key*64 + 32 + lg*8) ^ sz];
    }
    f32x4 S[2][4];
#pragma unroll
    for (int rg = 0; rg < 2; ++rg)
#pragma unroll
      for (int kt = 0; kt < 4; ++kt){
        f32x4 c = (f32x4)(0.0f);
        c = __builtin_amdgcn_mfma_f32_16x16x32_bf16(kf[kt][0], qf[rg][0], c, 0, 0, 0);
        c = __builtin_amdgcn_mfma_f32_16x16x32_bf16(kf[kt][1], qf[rg][1], c, 0, 0, 0);
        S[rg][kt] = c;
      }

    s16x4 pb[2][4];
#pragma unroll
    for (int rg = 0; rg < 2; ++rg){
      const float base = qposf[rg] - kbf - koffb;
#pragma unroll
      for (int kt = 0; kt < 4; ++kt)
#pragma unroll
        for (int r = 0; r < 4; ++r)
          S[rg][kt][r] = fmaf(-bs, fabsf(base - (float)(kt*16 + r)), S[rg][kt][r]);

      float a0 = fmaxf(fmaxf(S[rg][0][0], S[rg][0][1]), fmaxf(S[rg][0][2], S[rg][0][3]));
      float a1 = fmaxf(fmaxf(S[rg][1][0], S[rg][1][1]), fmaxf(S[rg][1][2], S[rg][1][3]));
      float a2 = fmaxf(fmaxf(S[rg][2][0], S[rg][2][1]), fmaxf(S[rg][2][2], S[rg][2][3]));
      float a3 = fmaxf(fmaxf(S[rg][3][0], S[rg][3][1]), fmaxf(S[rg][3][2], S[rg][3][3]));
      float mx = fmaxf(fmaxf(a0, a1), fmaxf(a2, a3));
      mx = fmaxf(mx, __shfl_xor(mx, 16, 64));
      mx = fmaxf(mx, __shfl_xor(mx, 32, 64));

      const float mo = mreg[rg];
      const float mn = fmaxf(mo, mx);
      const float scl = EXP2(mo - mn);
      mreg[rg] = mn;

      float p[16];
#pragma unroll
      for (int kt = 0; kt < 4; ++kt)
#pragma unroll
        for (int r = 0; r < 4; ++r)
          p[kt*4 + r] = EXP2(S[rg][kt][r] - mn);

      float s0 = (p[0]+p[1]) + (p[2]+p[3]);
      float s1 = (p[4]+p[5]) + (p[6]+p[7]);
      float s2 = (p[8]+p[9]) + (p[10]+p[11]);
      float s3 = (p[12]+p[13]) + (p[14]+p[15]);
      float sum = (s0+s1) + (s2+s3);
      sum += __shfl_xor(sum, 16, 64);
      sum += __shfl_xor(sum, 32, 64);
      lreg[rg] = lreg[rg] * scl + sum;

#pragma unroll
      for (int dt = 0; dt < 4; ++dt) acc[rg][dt] *= scl;

#pragma unroll
      for (int kt = 0; kt < 4; ++kt){
        union { uint32_t w[2]; s16x4 v; } u;
        u.w[0] = pk2(p[kt*4+0], p[kt*4+1]);
        u.w[1] = pk2(p[kt*4+2], p[kt*4+3]);
        pb[rg][kt] = u.v;
      }
    }

#pragma unroll
    for (int dt = 0; dt < 4; ++dt){
      const int d  = dt*16 + ln;
      const int sz = sw(d);
#pragma unroll
      for (int kt = 0; kt < 4; ++kt){
        const s16x4 vf = *(const s16x4*)&vb_[(d*64 + kt*16 + lg*4) ^ sz];
        acc[0][dt] = __builtin_amdgcn_mfma_f32_16x16x16bf16_1k(vf, pb[0][kt], acc[0][dt], 0, 0, 0);
        acc[1][dt] = __builtin_amdgcn_mfma_f32_16x16x16bf16_1k(vf, pb[1][kt], acc[1][dt], 0, 0, 0);
      }
    }

    if (kv + 1 < NT){
      stage_store(cur ^ 1);
      __syncthreads();
      cur ^= 1;
    }
  }

#pragma unroll
  for (int rg = 0; rg < 2; ++rg){
    const float inv = 1.0f / lreg[rg];
    float* op = Og + headoff + (size_t)(qb + rg*16 + ln) * DHEAD + lg*4;
#pragma unroll
    for (int dt = 0; dt < 4; ++dt){
      f4 o;
      o[0] = acc[rg][dt][0] * inv;
      o[1] = acc[rg][dt][1] * inv;
      o[2] = acc[rg][dt][2] * inv;
      o[3] = acc[rg][dt][3] * inv;
      *(f4*)(op + dt*16) = o;
    }
  }
}

extern "C" void kernel_launch(void* const* d_in, const int* in_sizes, int n_in,
                              void* d_out, int out_size, void* d_ws, size_t ws_size,
                              hipStream_t stream)
{
  const float* Q = (const float*)d_in[0];
  const float* K = (const float*)d_in[1];
  const float* V = (const float*)d_in[2];
  float* O = (float*)d_out;

  const size_t need = (size_t)NHEAD * T_LEN * DHEAD * 2 * 2;  // K + V^T bf16 = 16 MB
  if (ws_size >= need){
    u16* Kb = (u16*)d_ws;
    u16* VT = Kb + (size_t)NHEAD * T_LEN * DHEAD;
    hipLaunchKernelGGL(cvt_k,  dim3(2048), dim3(256), 0, stream, K, Kb);
    hipLaunchKernelGGL(cvt_vt, dim3(1024), dim3(256), 0, stream, V, VT);
    hipLaunchKernelGGL(alibi_attn3, dim3(1024), dim3(256), 0, stream, Q, Kb, VT, O);
  } else {
    hipLaunchKernelGGL(alibi_attn_fb, dim3(512), dim3(256), 0, stream, Q, K, V, O);
  }
}

// Round 8
// 114.812 us; speedup vs baseline: 9.5541x; 1.1117x over previous
//
#include <hip/hip_runtime.h>
#include <hip/hip_bf16.h>
#include <stdint.h>

typedef float f4    __attribute__((ext_vector_type(4)));
typedef float f32x4 __attribute__((ext_vector_type(4)));
typedef short s16x8 __attribute__((ext_vector_type(8)));
typedef short s16x4 __attribute__((ext_vector_type(4)));
typedef unsigned short u16;

#define T_LEN 4096
#define NHEAD 16
#define DHEAD 64
#define KVBLK 64
#define NT    (T_LEN / KVBLK)

#if __has_builtin(__builtin_amdgcn_exp2f)
#define EXP2(x) __builtin_amdgcn_exp2f(x)
#else
#define EXP2(x) exp2f(x)
#endif

// bf16 pack of a pair in 3 VALU: round-half-up then v_perm_b32 byte-select.
__device__ __forceinline__ uint32_t pk2(float a, float b){
  uint32_t ua = __builtin_bit_cast(uint32_t, a) + 0x8000u;
  uint32_t ub = __builtin_bit_cast(uint32_t, b) + 0x8000u;
  return __builtin_amdgcn_perm(ub, ua, 0x07060302u);
}
__device__ __forceinline__ int swk(int r){ return (r ^ (r >> 3)) & 7; }
__device__ __forceinline__ int sw(int r){ return swk(r) << 3; }

// ---------------- pre-pass: K fp32 -> bf16 (same layout) ----------------
__global__ __launch_bounds__(256)
void cvt_k(const float* __restrict__ K, u16* __restrict__ Kb){
  const size_t i = ((size_t)blockIdx.x * 256 + threadIdx.x) * 8;
  f4 a = *(const f4*)(K + i);
  f4 b = *(const f4*)(K + i + 4);
  union { uint32_t w[4]; s16x8 v; } u;
  u.w[0] = pk2(a[0], a[1]); u.w[1] = pk2(a[2], a[3]);
  u.w[2] = pk2(b[0], b[1]); u.w[3] = pk2(b[2], b[3]);
  *(s16x8*)(Kb + i) = u.v;
}

// ---------------- pre-pass: V fp32 [h][t][d] -> bf16 V^T [h][d][t] ----------------
__global__ __launch_bounds__(256)
void cvt_vt(const float* __restrict__ V, u16* __restrict__ VT){
  __shared__ u16 tile[64][66];
  const int h  = blockIdx.x >> 6;
  const int kt = blockIdx.x & 63;
  const int t  = threadIdx.x;
  const float* Vh = V + ((size_t)h * T_LEN + kt * 64) * DHEAD;

  const int r = t >> 2, c = (t & 3) * 16;
  f4 x0 = *(const f4*)(Vh + r*64 + c);
  f4 x1 = *(const f4*)(Vh + r*64 + c + 4);
  f4 x2 = *(const f4*)(Vh + r*64 + c + 8);
  f4 x3 = *(const f4*)(Vh + r*64 + c + 12);
  uint32_t* tp = (uint32_t*)&tile[r][c];
  tp[0] = pk2(x0[0],x0[1]); tp[1] = pk2(x0[2],x0[3]);
  tp[2] = pk2(x1[0],x1[1]); tp[3] = pk2(x1[2],x1[3]);
  tp[4] = pk2(x2[0],x2[1]); tp[5] = pk2(x2[2],x2[3]);
  tp[6] = pk2(x3[0],x3[1]); tp[7] = pk2(x3[2],x3[3]);
  __syncthreads();

  const int d = t >> 2, ks = (t & 3) * 16;
  u16* op = VT + ((size_t)h * DHEAD + d) * T_LEN + kt * 64 + ks;
  union { uint32_t w[4]; s16x8 v; } o0, o1;
#pragma unroll
  for (int q = 0; q < 4; ++q)
    o0.w[q] = (uint32_t)tile[ks + 2*q][d]     | ((uint32_t)tile[ks + 2*q + 1][d] << 16);
#pragma unroll
  for (int q = 0; q < 4; ++q)
    o1.w[q] = (uint32_t)tile[ks + 8 + 2*q][d] | ((uint32_t)tile[ks + 9 + 2*q][d] << 16);
  *(s16x8*)(op)     = o0.v;
  *(s16x8*)(op + 8) = o1.v;
}

// ---------------- main attention (ALiBi-windowed KV range) ----------------
__global__ __launch_bounds__(256, 4)
void alibi_attn4(const float* __restrict__ Qg,
                 const u16* __restrict__ Kb,
                 const u16* __restrict__ VTb,
                 float* __restrict__ Og)
{
  __shared__ u16 kbuf[2][KVBLK * DHEAD];   // [key][d] bf16, swizzled groups
  __shared__ u16 vbuf[2][DHEAD * KVBLK];   // [d][key] bf16, swizzled groups

  // XCD-aware bijective swizzle + head-interleaved fid so every XCD/CU gets
  // a balanced mix of head workloads (window length varies 2.5 .. 64 tiles).
  const int bid = blockIdx.x;
  const int fid = (bid & 7) * 128 + (bid >> 3);
  const int h  = fid & 15;     // head minor -> adjacent blocks differ in head
  const int qt = fid >> 4;

  const int tid  = threadIdx.x;
  const int wv   = tid >> 6;
  const int lane = tid & 63;
  const int lg   = lane >> 4;
  const int ln   = lane & 15;

  const int q0   = qt * 64;
  const int qrow = q0 + wv * 16 + ln;
  const float slope = exp2f(-0.5f * (float)(h + 1));
  const float cs = 0.125f * 1.44269504089f;
  const float bs = slope * 1.44269504089f;
  const size_t headoff = (size_t)h * T_LEN * DHEAD;

  // ---- ALiBi window: keys with bs*dist > 36 contribute < 2^-28 of row mass ----
  const int Di = (int)(36.0f / bs);
  int lo = (q0 - Di) >> 6;           if (lo < 0) lo = 0;
  int hi = (q0 + 63 + Di) >> 6;      if (hi > NT - 1) hi = NT - 1;

  // ---- Q fragments (B-operand of swapped QK^T) ----
  s16x8 qf0, qf1;
  {
    const float* qp = Qg + headoff + (size_t)qrow * DHEAD + lg * 8;
    f4 x = *(const f4*)qp;        f4 y = *(const f4*)(qp + 4);
    f4 z = *(const f4*)(qp + 32); f4 v = *(const f4*)(qp + 36);
    union { uint32_t w_[4]; s16x8 v_; } u0, u1;
    u0.w_[0] = pk2(x[0]*cs, x[1]*cs); u0.w_[1] = pk2(x[2]*cs, x[3]*cs);
    u0.w_[2] = pk2(y[0]*cs, y[1]*cs); u0.w_[3] = pk2(y[2]*cs, y[3]*cs);
    u1.w_[0] = pk2(z[0]*cs, z[1]*cs); u1.w_[1] = pk2(z[2]*cs, z[3]*cs);
    u1.w_[2] = pk2(v[0]*cs, v[1]*cs); u1.w_[3] = pk2(v[2]*cs, v[3]*cs);
    qf0 = u0.v_; qf1 = u1.v_;
  }

  f32x4 acc[4];
#pragma unroll
  for (int dt = 0; dt < 4; ++dt) acc[dt] = (f32x4)(0.0f);
  float lsum = 0.0f;
  const float base0 = (float)qrow - (float)(lg * 4);

  // ---- hoisted swizzled LDS read byte-offsets (loop-invariant) ----
  int koffs[4][2];
#pragma unroll
  for (int kt = 0; kt < 4; ++kt){
    const int key = kt*16 + ln, sz = sw(key);
    koffs[kt][0] = (((key*64      + lg*8) ^ sz)) * 2;
    koffs[kt][1] = (((key*64 + 32 + lg*8) ^ sz)) * 2;
  }
  int voffs[4][4];
#pragma unroll
  for (int dt = 0; dt < 4; ++dt){
    const int d = dt*16 + ln, sz = sw(d);
#pragma unroll
    for (int kt = 0; kt < 4; ++kt)
      voffs[dt][kt] = (((d*64 + kt*16 + lg*4) ^ sz)) * 2;
  }

  // ---- staging: linear LDS dest, inverse-swizzled global source ----
  const u16* Kh = Kb  + headoff;
  const u16* Vh = VTb + headoff;
  const int sA = wv * 128 + lane;
  const int sB = sA + 64;
  const int keyA = sA >> 3, gA = (sA & 7) ^ swk(keyA);
  const int keyB = sB >> 3, gB = (sB & 7) ^ swk(keyB);
  const int kidxA = keyA * 64 + gA * 8;
  const int kidxB = keyB * 64 + gB * 8;
  const int vidxA = keyA * T_LEN + gA * 8;
  const int vidxB = keyB * T_LEN + gB * 8;
  const int dstA = sA * 16, dstB = sB * 16;  // bytes, linear

  s16x8 rkA, rkB, rvA, rvB;
  auto ldregs = [&](int t){
    const u16* kp = Kh + (size_t)t * (KVBLK * DHEAD);
    const u16* vp = Vh + (size_t)t * KVBLK;
    rkA = *(const s16x8*)(kp + kidxA);  rkB = *(const s16x8*)(kp + kidxB);
    rvA = *(const s16x8*)(vp + vidxA);  rvB = *(const s16x8*)(vp + vidxB);
  };
  auto wrregs = [&](u16* kb_, u16* vb_){
    *(s16x8*)((char*)kb_ + dstA) = rkA;  *(s16x8*)((char*)kb_ + dstB) = rkB;
    *(s16x8*)((char*)vb_ + dstA) = rvA;  *(s16x8*)((char*)vb_ + dstB) = rvB;
  };

  auto compute = [&](const u16* kb_, const u16* vb_, int kv){
    // QK^T (swapped): S^T[key][q]
    f32x4 S[4];
    __builtin_amdgcn_s_setprio(1);
#pragma unroll
    for (int kt = 0; kt < 4; ++kt){
      s16x8 k0 = *(const s16x8*)((const char*)kb_ + koffs[kt][0]);
      s16x8 k1 = *(const s16x8*)((const char*)kb_ + koffs[kt][1]);
      f32x4 c = (f32x4)(0.0f);
      c = __builtin_amdgcn_mfma_f32_16x16x32_bf16(k0, qf0, c, 0, 0, 0);
      c = __builtin_amdgcn_mfma_f32_16x16x32_bf16(k1, qf1, c, 0, 0, 0);
      S[kt] = c;
    }
    __builtin_amdgcn_s_setprio(0);

    // bias + exp2 (no max tracking: softmax shift-invariant, scores bounded)
    const float bi = base0 - (float)(kv * KVBLK);
    float p[16];
#pragma unroll
    for (int kt = 0; kt < 4; ++kt)
#pragma unroll
      for (int r = 0; r < 4; ++r)
        p[kt*4 + r] = EXP2(fmaf(-bs, fabsf(bi - (float)(kt*16 + r)), S[kt][r]));

    lsum += (((p[0]+p[1]) + (p[2]+p[3])) + ((p[4]+p[5]) + (p[6]+p[7])))
          + (((p[8]+p[9]) + (p[10]+p[11])) + ((p[12]+p[13]) + (p[14]+p[15])));

    s16x4 pb[4];
#pragma unroll
    for (int kt = 0; kt < 4; ++kt){
      union { uint32_t w_[2]; s16x4 v_; } u;
      u.w_[0] = pk2(p[kt*4+0], p[kt*4+1]);
      u.w_[1] = pk2(p[kt*4+2], p[kt*4+3]);
      pb[kt] = u.v_;
    }

    // PV: O^T += V^T · P^T
    __builtin_amdgcn_s_setprio(1);
#pragma unroll
    for (int dt = 0; dt < 4; ++dt){
#pragma unroll
      for (int kt = 0; kt < 4; ++kt){
        const s16x4 vf = *(const s16x4*)((const char*)vb_ + voffs[dt][kt]);
        acc[dt] = __builtin_amdgcn_mfma_f32_16x16x16bf16_1k(vf, pb[kt], acc[dt], 0, 0, 0);
      }
    }
    __builtin_amdgcn_s_setprio(0);
  };

  ldregs(lo);
  wrregs(kbuf[0], vbuf[0]);
  __syncthreads();

  int t = lo;
#pragma unroll 1
  while (t + 1 < hi){
    // invariant: buf0 holds tile t; at least tiles t, t+1, and t+2<=hi exist
    ldregs(t + 1);
    compute(kbuf[0], vbuf[0], t);
    wrregs(kbuf[1], vbuf[1]);
    __syncthreads();
    ldregs(t + 2);
    compute(kbuf[1], vbuf[1], t + 1);
    wrregs(kbuf[0], vbuf[0]);
    __syncthreads();
    t += 2;
  }
  if (t < hi){
    // exactly two tiles left: t (buf0) and hi
    ldregs(t + 1);
    compute(kbuf[0], vbuf[0], t);
    wrregs(kbuf[1], vbuf[1]);
    __syncthreads();
    compute(kbuf[1], vbuf[1], t + 1);
  } else {
    // single tile left in buf0
    compute(kbuf[0], vbuf[0], t);
  }

  // ---- epilogue: cross-lane l reduction once, then normalize + store ----
  lsum += __shfl_xor(lsum, 16, 64);
  lsum += __shfl_xor(lsum, 32, 64);
  const float inv = 1.0f / lsum;
  float* op = Og + headoff + (size_t)qrow * DHEAD + lg * 4;
#pragma unroll
  for (int dt = 0; dt < 4; ++dt){
    f4 o;
    o[0] = acc[dt][0] * inv; o[1] = acc[dt][1] * inv;
    o[2] = acc[dt][2] * inv; o[3] = acc[dt][3] * inv;
    *(f4*)(op + dt*16) = o;
  }
}

// ---------------- fallback (round-5 kernel, used when ws too small) ----------------
__global__ __launch_bounds__(256, 2)
void alibi_attn_fb(const float* __restrict__ Qg,
                   const float* __restrict__ Kg,
                   const float* __restrict__ Vg,
                   float* __restrict__ Og)
{
  __shared__ u16 kbuf[2][KVBLK * DHEAD];
  __shared__ u16 vbuf[2][DHEAD * KVBLK];

  const int bid = blockIdx.x;
  const int fid = (bid & 7) * 64 + (bid >> 3);
  const int h  = fid >> 5;
  const int qt = fid & 31;

  const int tid  = threadIdx.x;
  const int wave = tid >> 6;
  const int lane = tid & 63;
  const int lg   = lane >> 4;
  const int ln   = lane & 15;

  const int qb = qt * 128 + wave * 32;
  const float slope = exp2f(-0.5f * (float)(h + 1));
  const float cs = 0.125f * 1.44269504089f;
  const float bs = slope * 1.44269504089f;
  const size_t headoff = (size_t)h * T_LEN * DHEAD;

  s16x8 qf[2][2];
#pragma unroll
  for (int rg = 0; rg < 2; ++rg)
#pragma unroll
    for (int dh = 0; dh < 2; ++dh){
      const float* qp = Qg + headoff + (size_t)(qb + rg*16 + ln) * DHEAD + dh*32 + lg*8;
      f4 x = *(const f4*)qp;
      f4 y = *(const f4*)(qp + 4);
      union { uint32_t w[4]; s16x8 v; } u;
      u.w[0] = pk2(x[0]*cs, x[1]*cs);
      u.w[1] = pk2(x[2]*cs, x[3]*cs);
      u.w[2] = pk2(y[0]*cs, y[1]*cs);
      u.w[3] = pk2(y[2]*cs, y[3]*cs);
      qf[rg][dh] = u.v;
    }

  f32x4 acc[2][4];
#pragma unroll
  for (int rg = 0; rg < 2; ++rg)
#pragma unroll
    for (int dt = 0; dt < 4; ++dt) acc[rg][dt] = (f32x4)(0.0f);
  float mreg[2] = {-1e30f, -1e30f};
  float lreg[2] = {0.0f, 0.0f};
  const float qposf[2] = {(float)(qb + ln), (float)(qb + 16 + ln)};
  const float koffb = (float)(lg * 4);

  f4 st4[8];
  const int vk0  = (tid >> 2) * 2;
  const int vseg = (tid & 3) * 16;
  const int krow = (tid - 128) >> 1;
  const int kseg = ((tid - 128) & 1) * 32;
  const float* Vb = Vg + headoff;
  const float* Kb_ = Kg + headoff;

  auto stage_load = [&](int kv){
    const int kb = kv * KVBLK;
    if (tid < 128){
      const float* vp = Vb + (size_t)(kb + vk0) * DHEAD + vseg;
      st4[0] = *(const f4*)(vp);      st4[1] = *(const f4*)(vp + 4);
      st4[2] = *(const f4*)(vp + 8);  st4[3] = *(const f4*)(vp + 12);
      st4[4] = *(const f4*)(vp + 64); st4[5] = *(const f4*)(vp + 68);
      st4[6] = *(const f4*)(vp + 72); st4[7] = *(const f4*)(vp + 76);
    } else {
      const float* kp = Kb_ + (size_t)(kb + krow) * DHEAD + kseg;
#pragma unroll
      for (int j = 0; j < 8; ++j) st4[j] = *(const f4*)(kp + j*4);
    }
  };
  auto stage_store = [&](int b){
    if (tid < 128){
#pragma unroll
      for (int i = 0; i < 16; ++i){
        const int d = vseg + i;
        uint32_t pr = pk2(st4[i>>2][i&3], st4[4 + (i>>2)][i&3]);
        *(uint32_t*)&vbuf[b][(d*64 + vk0) ^ sw(d)] = pr;
      }
    } else {
#pragma unroll
      for (int i = 0; i < 4; ++i){
        union { uint32_t w[4]; s16x8 v; } u;
        u.w[0] = pk2(st4[i*2][0],   st4[i*2][1]);
        u.w[1] = pk2(st4[i*2][2],   st4[i*2][3]);
        u.w[2] = pk2(st4[i*2+1][0], st4[i*2+1][1]);
        u.w[3] = pk2(st4[i*2+1][2], st4[i*2+1][3]);
        *(s16x8*)&kbuf[b][(krow*64 + kseg + i*8) ^ sw(krow)] = u.v;
      }
    }
  };

  stage_load(0);
  stage_store(0);
  __syncthreads();
  int cur = 0;

#pragma unroll 1
  for (int kv = 0; kv < NT; ++kv){
    if (kv + 1 < NT) stage_load(kv + 1);

    const float kbf = (float)(kv * KVBLK);
    const u16* kb_ = kbuf[cur];
    const u16* vb_ = vbuf[cur];

    s16x8 kf[4][2];
#pragma unroll
    for (int kt = 0; kt < 4; ++kt){
      const int key = kt*16 + ln;
      const int sz  = sw(key);
      kf[kt][0] = *(const s16x8*)&kb_[(key*64 +      lg*8) ^ sz];
      kf[kt][1] = *(const s16x8*)&kb_[(key*64 + 32 + lg*8) ^ sz];
    }
    f32x4 S[2][4];
#pragma unroll
    for (int rg = 0; rg < 2; ++rg)
#pragma unroll
      for (int kt = 0; kt < 4; ++kt){
        f32x4 c = (f32x4)(0.0f);
        c = __builtin_amdgcn_mfma_f32_16x16x32_bf16(kf[kt][0], qf[rg][0], c, 0, 0, 0);
        c = __builtin_amdgcn_mfma_f32_16x16x32_bf16(kf[kt][1], qf[rg][1], c, 0, 0, 0);
        S[rg][kt] = c;
      }

    s16x4 pb[2][4];
#pragma unroll
    for (int rg = 0; rg < 2; ++rg){
      const float base = qposf[rg] - kbf - koffb;
#pragma unroll
      for (int kt = 0; kt < 4; ++kt)
#pragma unroll
        for (int r = 0; r < 4; ++r)
          S[rg][kt][r] = fmaf(-bs, fabsf(base - (float)(kt*16 + r)), S[rg][kt][r]);

      float a0 = fmaxf(fmaxf(S[rg][0][0], S[rg][0][1]), fmaxf(S[rg][0][2], S[rg][0][3]));
      float a1 = fmaxf(fmaxf(S[rg][1][0], S[rg][1][1]), fmaxf(S[rg][1][2], S[rg][1][3]));
      float a2 = fmaxf(fmaxf(S[rg][2][0], S[rg][2][1]), fmaxf(S[rg][2][2], S[rg][2][3]));
      float a3 = fmaxf(fmaxf(S[rg][3][0], S[rg][3][1]), fmaxf(S[rg][3][2], S[rg][3][3]));
      float mx = fmaxf(fmaxf(a0, a1), fmaxf(a2, a3));
      mx = fmaxf(mx, __shfl_xor(mx, 16, 64));
      mx = fmaxf(mx, __shfl_xor(mx, 32, 64));

      const float mo = mreg[rg];
      const float mn = fmaxf(mo, mx);
      const float scl = EXP2(mo - mn);
      mreg[rg] = mn;

      float p[16];
#pragma unroll
      for (int kt = 0; kt < 4; ++kt)
#pragma unroll
        for (int r = 0; r < 4; ++r)
          p[kt*4 + r] = EXP2(S[rg][kt][r] - mn);

      float s0 = (p[0]+p[1]) + (p[2]+p[3]);
      float s1 = (p[4]+p[5]) + (p[6]+p[7]);
      float s2 = (p[8]+p[9]) + (p[10]+p[11]);
      float s3 = (p[12]+p[13]) + (p[14]+p[15]);
      float sum = (s0+s1) + (s2+s3);
      sum += __shfl_xor(sum, 16, 64);
      sum += __shfl_xor(sum, 32, 64);
      lreg[rg] = lreg[rg] * scl + sum;

#pragma unroll
      for (int dt = 0; dt < 4; ++dt) acc[rg][dt] *= scl;

#pragma unroll
      for (int kt = 0; kt < 4; ++kt){
        union { uint32_t w[2]; s16x4 v; } u;
        u.w[0] = pk2(p[kt*4+0], p[kt*4+1]);
        u.w[1] = pk2(p[kt*4+2], p[kt*4+3]);
        pb[rg][kt] = u.v;
      }
    }

#pragma unroll
    for (int dt = 0; dt < 4; ++dt){
      const int d  = dt*16 + ln;
      const int sz = sw(d);
#pragma unroll
      for (int kt = 0; kt < 4; ++kt){
        const s16x4 vf = *(const s16x4*)&vb_[(d*64 + kt*16 + lg*4) ^ sz];
        acc[0][dt] = __builtin_amdgcn_mfma_f32_16x16x16bf16_1k(vf, pb[0][kt], acc[0][dt], 0, 0, 0);
        acc[1][dt] = __builtin_amdgcn_mfma_f32_16x16x16bf16_1k(vf, pb[1][kt], acc[1][dt], 0, 0, 0);
      }
    }

    if (kv + 1 < NT){
      stage_store(cur ^ 1);
      __syncthreads();
      cur ^= 1;
    }
  }

#pragma unroll
  for (int rg = 0; rg < 2; ++rg){
    const float inv = 1.0f / lreg[rg];
    float* op = Og + headoff + (size_t)(qb + rg*16 + ln) * DHEAD + lg*4;
#pragma unroll
    for (int dt = 0; dt < 4; ++dt){
      f4 o;
      o[0] = acc[rg][dt][0] * inv;
      o[1] = acc[rg][dt][1] * inv;
      o[2] = acc[rg][dt][2] * inv;
      o[3] = acc[rg][dt][3] * inv;
      *(f4*)(op + dt*16) = o;
    }
  }
}

extern "C" void kernel_launch(void* const* d_in, const int* in_sizes, int n_in,
                              void* d_out, int out_size, void* d_ws, size_t ws_size,
                              hipStream_t stream)
{
  const float* Q = (const float*)d_in[0];
  const float* K = (const float*)d_in[1];
  const float* V = (const float*)d_in[2];
  float* O = (float*)d_out;

  const size_t need = (size_t)NHEAD * T_LEN * DHEAD * 2 * 2;  // K + V^T bf16 = 16 MB
  if (ws_size >= need){
    u16* Kb = (u16*)d_ws;
    u16* VT = Kb + (size_t)NHEAD * T_LEN * DHEAD;
    hipLaunchKernelGGL(cvt_k,  dim3(2048), dim3(256), 0, stream, K, Kb);
    hipLaunchKernelGGL(cvt_vt, dim3(1024), dim3(256), 0, stream, V, VT);
    hipLaunchKernelGGL(alibi_attn4, dim3(1024), dim3(256), 0, stream, Q, Kb, VT, O);
  } else {
    hipLaunchKernelGGL(alibi_attn_fb, dim3(512), dim3(256), 0, stream, Q, K, V, O);
  }
}

// Round 9
// 81.603 us; speedup vs baseline: 13.4422x; 1.4070x over previous
//
#include <hip/hip_runtime.h>
#include <hip/hip_bf16.h>
#include <stdint.h>

typedef float f4    __attribute__((ext_vector_type(4)));
typedef float f32x4 __attribute__((ext_vector_type(4)));
typedef short s16x8 __attribute__((ext_vector_type(8)));
typedef short s16x4 __attribute__((ext_vector_type(4)));
typedef unsigned short u16;

#define T_LEN 4096
#define NHEAD 16
#define DHEAD 64
#define KVBLK 64
#define NT    (T_LEN / KVBLK)

#if __has_builtin(__builtin_amdgcn_exp2f)
#define EXP2(x) __builtin_amdgcn_exp2f(x)
#else
#define EXP2(x) exp2f(x)
#endif

// partial slot: 64 rows x 64 d acc + 64 lsum = 4160 floats
#define SLOT_F 4160
#define NSLOTS 1728
#define CONV_BYTES (16u * 4096u * 64u * 2u * 2u)            // Kb + VT bf16 = 16.78 MB
#define CHUNK_BYTES ((size_t)CONV_BYTES + (size_t)NSLOTS * SLOT_F * 4u)

__device__ __forceinline__ uint32_t pk2(float a, float b){
  uint32_t ua = __builtin_bit_cast(uint32_t, a) + 0x8000u;
  uint32_t ub = __builtin_bit_cast(uint32_t, b) + 0x8000u;
  return __builtin_amdgcn_perm(ub, ua, 0x07060302u);
}
__device__ __forceinline__ int swk(int r){ return (r ^ (r >> 3)) & 7; }
__device__ __forceinline__ int sw(int r){ return swk(r) << 3; }
__device__ __forceinline__ int slotbase(int h){
  return (h <= 9) ? (h - 8) * 128 : (h == 10 ? 256 : 448 + (h - 11) * 256);
}

// ---------------- pre-pass: K fp32 -> bf16 ----------------
__global__ __launch_bounds__(256)
void cvt_k(const float* __restrict__ K, u16* __restrict__ Kb){
  const size_t i = ((size_t)blockIdx.x * 256 + threadIdx.x) * 8;
  f4 a = *(const f4*)(K + i);
  f4 b = *(const f4*)(K + i + 4);
  union { uint32_t w[4]; s16x8 v; } u;
  u.w[0] = pk2(a[0], a[1]); u.w[1] = pk2(a[2], a[3]);
  u.w[2] = pk2(b[0], b[1]); u.w[3] = pk2(b[2], b[3]);
  *(s16x8*)(Kb + i) = u.v;
}

// ---------------- pre-pass: V fp32 [h][t][d] -> bf16 V^T [h][d][t] ----------------
__global__ __launch_bounds__(256)
void cvt_vt(const float* __restrict__ V, u16* __restrict__ VT){
  __shared__ u16 tile[64][66];
  const int h  = blockIdx.x >> 6;
  const int kt = blockIdx.x & 63;
  const int t  = threadIdx.x;
  const float* Vh = V + ((size_t)h * T_LEN + kt * 64) * DHEAD;

  const int r = t >> 2, c = (t & 3) * 16;
  f4 x0 = *(const f4*)(Vh + r*64 + c);
  f4 x1 = *(const f4*)(Vh + r*64 + c + 4);
  f4 x2 = *(const f4*)(Vh + r*64 + c + 8);
  f4 x3 = *(const f4*)(Vh + r*64 + c + 12);
  uint32_t* tp = (uint32_t*)&tile[r][c];
  tp[0] = pk2(x0[0],x0[1]); tp[1] = pk2(x0[2],x0[3]);
  tp[2] = pk2(x1[0],x1[1]); tp[3] = pk2(x1[2],x1[3]);
  tp[4] = pk2(x2[0],x2[1]); tp[5] = pk2(x2[2],x2[3]);
  tp[6] = pk2(x3[0],x3[1]); tp[7] = pk2(x3[2],x3[3]);
  __syncthreads();

  const int d = t >> 2, ks = (t & 3) * 16;
  u16* op = VT + ((size_t)h * DHEAD + d) * T_LEN + kt * 64 + ks;
  union { uint32_t w[4]; s16x8 v; } o0, o1;
#pragma unroll
  for (int q = 0; q < 4; ++q)
    o0.w[q] = (uint32_t)tile[ks + 2*q][d]     | ((uint32_t)tile[ks + 2*q + 1][d] << 16);
#pragma unroll
  for (int q = 0; q < 4; ++q)
    o1.w[q] = (uint32_t)tile[ks + 8 + 2*q][d] | ((uint32_t)tile[ks + 9 + 2*q][d] << 16);
  *(s16x8*)(op)     = o0.v;
  *(s16x8*)(op + 8) = o1.v;
}

// ---------------- chunked attention (windowed + KV-split, partial combine) ----------------
__global__ __launch_bounds__(256, 4)
void alibi_attn5(const float* __restrict__ Qg,
                 const u16* __restrict__ Kb,
                 const u16* __restrict__ VTb,
                 float* __restrict__ Og,
                 float* __restrict__ part)
{
  __shared__ u16 kbuf[2][KVBLK * DHEAD];
  __shared__ u16 vbuf[2][DHEAD * KVBLK];

  // bid -> (h, qt, chunk c of n). Heavy heads first (better packing).
  const int bid = blockIdx.x;
  int h, qt, c, n;
  if (bid < 1280){            // h 11..15, NC=4
    h = 11 + (bid >> 8); int r = bid & 255; qt = r >> 2; c = r & 3; n = 4;
  } else if (bid < 1472){     // h 10, NC=3
    int r = bid - 1280; h = 10; qt = r / 3; c = r - qt * 3; n = 3;
  } else if (bid < 1728){     // h 8..9, NC=2
    int r = bid - 1472; h = 8 + (r >> 7); r &= 127; qt = r >> 1; c = r & 1; n = 2;
  } else {                    // h 0..7, NC=1
    int r = bid - 1728; h = r >> 6; qt = r & 63; c = 0; n = 1;
  }

  const int tid  = threadIdx.x;
  const int wv   = tid >> 6;
  const int lane = tid & 63;
  const int lg   = lane >> 4;
  const int ln   = lane & 15;

  const int q0   = qt * 64;
  const int qrow = q0 + wv * 16 + ln;
  const float slope = exp2f(-0.5f * (float)(h + 1));
  const float cs = 0.125f * 1.44269504089f;
  const float bs = slope * 1.44269504089f;
  const size_t headoff = (size_t)h * T_LEN * DHEAD;

  // ALiBi window (keys with bs*dist > 36 are negligible), then chunk c of n
  const int Di = (int)(36.0f / bs);
  int lo = (q0 - Di) >> 6;           if (lo < 0) lo = 0;
  int hi = (q0 + 63 + Di) >> 6;      if (hi > NT - 1) hi = NT - 1;
  const int len = hi - lo + 1;
  const int start = lo + (c * len) / n;
  const int end   = lo + ((c + 1) * len) / n;   // exclusive

  // ---- Q fragments ----
  s16x8 qf0, qf1;
  {
    const float* qp = Qg + headoff + (size_t)qrow * DHEAD + lg * 8;
    f4 x = *(const f4*)qp;        f4 y = *(const f4*)(qp + 4);
    f4 z = *(const f4*)(qp + 32); f4 v = *(const f4*)(qp + 36);
    union { uint32_t w_[4]; s16x8 v_; } u0, u1;
    u0.w_[0] = pk2(x[0]*cs, x[1]*cs); u0.w_[1] = pk2(x[2]*cs, x[3]*cs);
    u0.w_[2] = pk2(y[0]*cs, y[1]*cs); u0.w_[3] = pk2(y[2]*cs, y[3]*cs);
    u1.w_[0] = pk2(z[0]*cs, z[1]*cs); u1.w_[1] = pk2(z[2]*cs, z[3]*cs);
    u1.w_[2] = pk2(v[0]*cs, v[1]*cs); u1.w_[3] = pk2(v[2]*cs, v[3]*cs);
    qf0 = u0.v_; qf1 = u1.v_;
  }

  f32x4 acc[4];
#pragma unroll
  for (int dt = 0; dt < 4; ++dt) acc[dt] = (f32x4)(0.0f);
  float lsum = 0.0f;
  const float base0 = (float)qrow - (float)(lg * 4);

  // ---- hoisted swizzled LDS read byte-offsets ----
  int koffs[4][2];
#pragma unroll
  for (int kt = 0; kt < 4; ++kt){
    const int key = kt*16 + ln, sz = sw(key);
    koffs[kt][0] = (((key*64      + lg*8) ^ sz)) * 2;
    koffs[kt][1] = (((key*64 + 32 + lg*8) ^ sz)) * 2;
  }
  int voffs[4][4];
#pragma unroll
  for (int dt = 0; dt < 4; ++dt){
    const int d = dt*16 + ln, sz = sw(d);
#pragma unroll
    for (int kt = 0; kt < 4; ++kt)
      voffs[dt][kt] = (((d*64 + kt*16 + lg*4) ^ sz)) * 2;
  }

  // ---- staging: linear LDS dest, inverse-swizzled global source ----
  const u16* Kh = Kb  + headoff;
  const u16* Vh = VTb + headoff;
  const int sA = wv * 128 + lane;
  const int sB = sA + 64;
  const int keyA = sA >> 3, gA = (sA & 7) ^ swk(keyA);
  const int keyB = sB >> 3, gB = (sB & 7) ^ swk(keyB);
  const int kidxA = keyA * 64 + gA * 8;
  const int kidxB = keyB * 64 + gB * 8;
  const int vidxA = keyA * T_LEN + gA * 8;
  const int vidxB = keyB * T_LEN + gB * 8;
  const int dstA = sA * 16, dstB = sB * 16;

  s16x8 rkA, rkB, rvA, rvB;
  auto ldregs = [&](int t){
    const u16* kp = Kh + (size_t)t * (KVBLK * DHEAD);
    const u16* vp = Vh + (size_t)t * KVBLK;
    rkA = *(const s16x8*)(kp + kidxA);  rkB = *(const s16x8*)(kp + kidxB);
    rvA = *(const s16x8*)(vp + vidxA);  rvB = *(const s16x8*)(vp + vidxB);
  };
  auto wrregs = [&](u16* kb_, u16* vb_){
    *(s16x8*)((char*)kb_ + dstA) = rkA;  *(s16x8*)((char*)kb_ + dstB) = rkB;
    *(s16x8*)((char*)vb_ + dstA) = rvA;  *(s16x8*)((char*)vb_ + dstB) = rvB;
  };

  auto compute = [&](const u16* kb_, const u16* vb_, int kv){
    f32x4 S[4];
    __builtin_amdgcn_s_setprio(1);
#pragma unroll
    for (int kt = 0; kt < 4; ++kt){
      s16x8 k0 = *(const s16x8*)((const char*)kb_ + koffs[kt][0]);
      s16x8 k1 = *(const s16x8*)((const char*)kb_ + koffs[kt][1]);
      f32x4 cc = (f32x4)(0.0f);
      cc = __builtin_amdgcn_mfma_f32_16x16x32_bf16(k0, qf0, cc, 0, 0, 0);
      cc = __builtin_amdgcn_mfma_f32_16x16x32_bf16(k1, qf1, cc, 0, 0, 0);
      S[kt] = cc;
    }
    __builtin_amdgcn_s_setprio(0);

    const float bi = base0 - (float)(kv * KVBLK);
    float p[16];
#pragma unroll
    for (int kt = 0; kt < 4; ++kt)
#pragma unroll
      for (int r = 0; r < 4; ++r)
        p[kt*4 + r] = EXP2(fmaf(-bs, fabsf(bi - (float)(kt*16 + r)), S[kt][r]));

    lsum += (((p[0]+p[1]) + (p[2]+p[3])) + ((p[4]+p[5]) + (p[6]+p[7])))
          + (((p[8]+p[9]) + (p[10]+p[11])) + ((p[12]+p[13]) + (p[14]+p[15])));

    s16x4 pb[4];
#pragma unroll
    for (int kt = 0; kt < 4; ++kt){
      union { uint32_t w_[2]; s16x4 v_; } u;
      u.w_[0] = pk2(p[kt*4+0], p[kt*4+1]);
      u.w_[1] = pk2(p[kt*4+2], p[kt*4+3]);
      pb[kt] = u.v_;
    }

    __builtin_amdgcn_s_setprio(1);
#pragma unroll
    for (int dt = 0; dt < 4; ++dt){
#pragma unroll
      for (int kt = 0; kt < 4; ++kt){
        const s16x4 vf = *(const s16x4*)((const char*)vb_ + voffs[dt][kt]);
        acc[dt] = __builtin_amdgcn_mfma_f32_16x16x16bf16_1k(vf, pb[kt], acc[dt], 0, 0, 0);
      }
    }
    __builtin_amdgcn_s_setprio(0);
  };

  if (start < end){
    ldregs(start);
    wrregs(kbuf[0], vbuf[0]);
    __syncthreads();

    const int hi_i = end - 1;
    int t = start;
#pragma unroll 1
    while (t + 1 < hi_i){
      ldregs(t + 1);
      compute(kbuf[0], vbuf[0], t);
      wrregs(kbuf[1], vbuf[1]);
      __syncthreads();
      ldregs(t + 2);
      compute(kbuf[1], vbuf[1], t + 1);
      wrregs(kbuf[0], vbuf[0]);
      __syncthreads();
      t += 2;
    }
    if (t < hi_i){
      ldregs(t + 1);
      compute(kbuf[0], vbuf[0], t);
      wrregs(kbuf[1], vbuf[1]);
      __syncthreads();
      compute(kbuf[1], vbuf[1], t + 1);
    } else {
      compute(kbuf[0], vbuf[0], t);
    }
  }

  // ---- row lsum reduce (lanes lg=0..3 hold partial sums of same row) ----
  lsum += __shfl_xor(lsum, 16, 64);
  lsum += __shfl_xor(lsum, 32, 64);

  if (n == 1){
    const float inv = 1.0f / lsum;
    float* op = Og + headoff + (size_t)qrow * DHEAD + lg * 4;
#pragma unroll
    for (int dt = 0; dt < 4; ++dt){
      f4 o;
      o[0] = acc[dt][0] * inv; o[1] = acc[dt][1] * inv;
      o[2] = acc[dt][2] * inv; o[3] = acc[dt][3] * inv;
      *(f4*)(op + dt*16) = o;
    }
  } else {
    float* slot = part + (size_t)(slotbase(h) + qt * n + c) * SLOT_F;
    const int row = wv * 16 + ln;
    float* op = slot + row * 64 + lg * 4;
#pragma unroll
    for (int dt = 0; dt < 4; ++dt)
      *(f4*)(op + dt*16) = acc[dt];
    if (lg == 0) slot[4096 + row] = lsum;
  }
}

// ---------------- combine partials for h 8..15 ----------------
__global__ __launch_bounds__(256)
void combine_k(const float* __restrict__ part, float* __restrict__ Og){
  const int h  = 8 + (blockIdx.x >> 6);
  const int qt = blockIdx.x & 63;
  const int n  = (h <= 9) ? 2 : (h == 10 ? 3 : 4);
  const int sb = slotbase(h) + qt * n;

  const int t   = threadIdx.x;
  const int row = t >> 2;
  const int seg = (t & 3) * 16;

  f4 a0 = (f4)(0.0f), a1 = (f4)(0.0f), a2 = (f4)(0.0f), a3 = (f4)(0.0f);
  float l = 0.0f;
#pragma unroll 1
  for (int c = 0; c < n; ++c){
    const float* sp = part + (size_t)(sb + c) * SLOT_F;
    const float* rp = sp + row * 64 + seg;
    a0 += *(const f4*)(rp);
    a1 += *(const f4*)(rp + 4);
    a2 += *(const f4*)(rp + 8);
    a3 += *(const f4*)(rp + 12);
    l  += sp[4096 + row];
  }
  const float inv = 1.0f / l;
  float* op = Og + (((size_t)h * T_LEN + qt * 64 + row) * DHEAD) + seg;
  f4 o0, o1, o2, o3;
  o0[0]=a0[0]*inv; o0[1]=a0[1]*inv; o0[2]=a0[2]*inv; o0[3]=a0[3]*inv;
  o1[0]=a1[0]*inv; o1[1]=a1[1]*inv; o1[2]=a1[2]*inv; o1[3]=a1[3]*inv;
  o2[0]=a2[0]*inv; o2[1]=a2[1]*inv; o2[2]=a2[2]*inv; o2[3]=a2[3]*inv;
  o3[0]=a3[0]*inv; o3[1]=a3[1]*inv; o3[2]=a3[2]*inv; o3[3]=a3[3]*inv;
  *(f4*)(op)      = o0;
  *(f4*)(op + 4)  = o1;
  *(f4*)(op + 8)  = o2;
  *(f4*)(op + 12) = o3;
}

// ---------------- windowed, unsplit kernel (ws >= 16.8MB fallback; round-8) ----------------
__global__ __launch_bounds__(256, 4)
void alibi_attn4(const float* __restrict__ Qg,
                 const u16* __restrict__ Kb,
                 const u16* __restrict__ VTb,
                 float* __restrict__ Og)
{
  __shared__ u16 kbuf[2][KVBLK * DHEAD];
  __shared__ u16 vbuf[2][DHEAD * KVBLK];

  const int bid = blockIdx.x;
  const int fid = (bid & 7) * 128 + (bid >> 3);
  const int h  = fid & 15;
  const int qt = fid >> 4;

  const int tid  = threadIdx.x;
  const int wv   = tid >> 6;
  const int lane = tid & 63;
  const int lg   = lane >> 4;
  const int ln   = lane & 15;

  const int q0   = qt * 64;
  const int qrow = q0 + wv * 16 + ln;
  const float slope = exp2f(-0.5f * (float)(h + 1));
  const float cs = 0.125f * 1.44269504089f;
  const float bs = slope * 1.44269504089f;
  const size_t headoff = (size_t)h * T_LEN * DHEAD;

  const int Di = (int)(36.0f / bs);
  int lo = (q0 - Di) >> 6;           if (lo < 0) lo = 0;
  int hi = (q0 + 63 + Di) >> 6;      if (hi > NT - 1) hi = NT - 1;

  s16x8 qf0, qf1;
  {
    const float* qp = Qg + headoff + (size_t)qrow * DHEAD + lg * 8;
    f4 x = *(const f4*)qp;        f4 y = *(const f4*)(qp + 4);
    f4 z = *(const f4*)(qp + 32); f4 v = *(const f4*)(qp + 36);
    union { uint32_t w_[4]; s16x8 v_; } u0, u1;
    u0.w_[0] = pk2(x[0]*cs, x[1]*cs); u0.w_[1] = pk2(x[2]*cs, x[3]*cs);
    u0.w_[2] = pk2(y[0]*cs, y[1]*cs); u0.w_[3] = pk2(y[2]*cs, y[3]*cs);
    u1.w_[0] = pk2(z[0]*cs, z[1]*cs); u1.w_[1] = pk2(z[2]*cs, z[3]*cs);
    u1.w_[2] = pk2(v[0]*cs, v[1]*cs); u1.w_[3] = pk2(v[2]*cs, v[3]*cs);
    qf0 = u0.v_; qf1 = u1.v_;
  }

  f32x4 acc[4];
#pragma unroll
  for (int dt = 0; dt < 4; ++dt) acc[dt] = (f32x4)(0.0f);
  float lsum = 0.0f;
  const float base0 = (float)qrow - (float)(lg * 4);

  int koffs[4][2];
#pragma unroll
  for (int kt = 0; kt < 4; ++kt){
    const int key = kt*16 + ln, sz = sw(key);
    koffs[kt][0] = (((key*64      + lg*8) ^ sz)) * 2;
    koffs[kt][1] = (((key*64 + 32 + lg*8) ^ sz)) * 2;
  }
  int voffs[4][4];
#pragma unroll
  for (int dt = 0; dt < 4; ++dt){
    const int d = dt*16 + ln, sz = sw(d);
#pragma unroll
    for (int kt = 0; kt < 4; ++kt)
      voffs[dt][kt] = (((d*64 + kt*16 + lg*4) ^ sz)) * 2;
  }

  const u16* Kh = Kb  + headoff;
  const u16* Vh = VTb + headoff;
  const int sA = wv * 128 + lane;
  const int sB = sA + 64;
  const int keyA = sA >> 3, gA = (sA & 7) ^ swk(keyA);
  const int keyB = sB >> 3, gB = (sB & 7) ^ swk(keyB);
  const int kidxA = keyA * 64 + gA * 8;
  const int kidxB = keyB * 64 + gB * 8;
  const int vidxA = keyA * T_LEN + gA * 8;
  const int vidxB = keyB * T_LEN + gB * 8;
  const int dstA = sA * 16, dstB = sB * 16;

  s16x8 rkA, rkB, rvA, rvB;
  auto ldregs = [&](int t){
    const u16* kp = Kh + (size_t)t * (KVBLK * DHEAD);
    const u16* vp = Vh + (size_t)t * KVBLK;
    rkA = *(const s16x8*)(kp + kidxA);  rkB = *(const s16x8*)(kp + kidxB);
    rvA = *(const s16x8*)(vp + vidxA);  rvB = *(const s16x8*)(vp + vidxB);
  };
  auto wrregs = [&](u16* kb_, u16* vb_){
    *(s16x8*)((char*)kb_ + dstA) = rkA;  *(s16x8*)((char*)kb_ + dstB) = rkB;
    *(s16x8*)((char*)vb_ + dstA) = rvA;  *(s16x8*)((char*)vb_ + dstB) = rvB;
  };

  auto compute = [&](const u16* kb_, const u16* vb_, int kv){
    f32x4 S[4];
    __builtin_amdgcn_s_setprio(1);
#pragma unroll
    for (int kt = 0; kt < 4; ++kt){
      s16x8 k0 = *(const s16x8*)((const char*)kb_ + koffs[kt][0]);
      s16x8 k1 = *(const s16x8*)((const char*)kb_ + koffs[kt][1]);
      f32x4 cc = (f32x4)(0.0f);
      cc = __builtin_amdgcn_mfma_f32_16x16x32_bf16(k0, qf0, cc, 0, 0, 0);
      cc = __builtin_amdgcn_mfma_f32_16x16x32_bf16(k1, qf1, cc, 0, 0, 0);
      S[kt] = cc;
    }
    __builtin_amdgcn_s_setprio(0);

    const float bi = base0 - (float)(kv * KVBLK);
    float p[16];
#pragma unroll
    for (int kt = 0; kt < 4; ++kt)
#pragma unroll
      for (int r = 0; r < 4; ++r)
        p[kt*4 + r] = EXP2(fmaf(-bs, fabsf(bi - (float)(kt*16 + r)), S[kt][r]));

    lsum += (((p[0]+p[1]) + (p[2]+p[3])) + ((p[4]+p[5]) + (p[6]+p[7])))
          + (((p[8]+p[9]) + (p[10]+p[11])) + ((p[12]+p[13]) + (p[14]+p[15])));

    s16x4 pb[4];
#pragma unroll
    for (int kt = 0; kt < 4; ++kt){
      union { uint32_t w_[2]; s16x4 v_; } u;
      u.w_[0] = pk2(p[kt*4+0], p[kt*4+1]);
      u.w_[1] = pk2(p[kt*4+2], p[kt*4+3]);
      pb[kt] = u.v_;
    }

    __builtin_amdgcn_s_setprio(1);
#pragma unroll
    for (int dt = 0; dt < 4; ++dt){
#pragma unroll
      for (int kt = 0; kt < 4; ++kt){
        const s16x4 vf = *(const s16x4*)((const char*)vb_ + voffs[dt][kt]);
        acc[dt] = __builtin_amdgcn_mfma_f32_16x16x16bf16_1k(vf, pb[kt], acc[dt], 0, 0, 0);
      }
    }
    __builtin_amdgcn_s_setprio(0);
  };

  ldregs(lo);
  wrregs(kbuf[0], vbuf[0]);
  __syncthreads();

  int t = lo;
#pragma unroll 1
  while (t + 1 < hi){
    ldregs(t + 1);
    compute(kbuf[0], vbuf[0], t);
    wrregs(kbuf[1], vbuf[1]);
    __syncthreads();
    ldregs(t + 2);
    compute(kbuf[1], vbuf[1], t + 1);
    wrregs(kbuf[0], vbuf[0]);
    __syncthreads();
    t += 2;
  }
  if (t < hi){
    ldregs(t + 1);
    compute(kbuf[0], vbuf[0], t);
    wrregs(kbuf[1], vbuf[1]);
    __syncthreads();
    compute(kbuf[1], vbuf[1], t + 1);
  } else {
    compute(kbuf[0], vbuf[0], t);
  }

  lsum += __shfl_xor(lsum, 16, 64);
  lsum += __shfl_xor(lsum, 32, 64);
  const float inv = 1.0f / lsum;
  float* op = Og + headoff + (size_t)qrow * DHEAD + lg * 4;
#pragma unroll
  for (int dt = 0; dt < 4; ++dt){
    f4 o;
    o[0] = acc[dt][0] * inv; o[1] = acc[dt][1] * inv;
    o[2] = acc[dt][2] * inv; o[3] = acc[dt][3] * inv;
    *(f4*)(op + dt*16) = o;
  }
}

// ---------------- no-ws fallback (round-5 kernel) ----------------
__global__ __launch_bounds__(256, 2)
void alibi_attn_fb(const float* __restrict__ Qg,
                   const float* __restrict__ Kg,
                   const float* __restrict__ Vg,
                   float* __restrict__ Og)
{
  __shared__ u16 kbuf[2][KVBLK * DHEAD];
  __shared__ u16 vbuf[2][DHEAD * KVBLK];

  const int bid = blockIdx.x;
  const int fid = (bid & 7) * 64 + (bid >> 3);
  const int h  = fid >> 5;
  const int qt = fid & 31;

  const int tid  = threadIdx.x;
  const int wave = tid >> 6;
  const int lane = tid & 63;
  const int lg   = lane >> 4;
  const int ln   = lane & 15;

  const int qb = qt * 128 + wave * 32;
  const float slope = exp2f(-0.5f * (float)(h + 1));
  const float cs = 0.125f * 1.44269504089f;
  const float bs = slope * 1.44269504089f;
  const size_t headoff = (size_t)h * T_LEN * DHEAD;

  s16x8 qf[2][2];
#pragma unroll
  for (int rg = 0; rg < 2; ++rg)
#pragma unroll
    for (int dh = 0; dh < 2; ++dh){
      const float* qp = Qg + headoff + (size_t)(qb + rg*16 + ln) * DHEAD + dh*32 + lg*8;
      f4 x = *(const f4*)qp;
      f4 y = *(const f4*)(qp + 4);
      union { uint32_t w[4]; s16x8 v; } u;
      u.w[0] = pk2(x[0]*cs, x[1]*cs);
      u.w[1] = pk2(x[2]*cs, x[3]*cs);
      u.w[2] = pk2(y[0]*cs, y[1]*cs);
      u.w[3] = pk2(y[2]*cs, y[3]*cs);
      qf[rg][dh] = u.v;
    }

  f32x4 acc[2][4];
#pragma unroll
  for (int rg = 0; rg < 2; ++rg)
#pragma unroll
    for (int dt = 0; dt < 4; ++dt) acc[rg][dt] = (f32x4)(0.0f);
  float mreg[2] = {-1e30f, -1e30f};
  float lreg[2] = {0.0f, 0.0f};
  const float qposf[2] = {(float)(qb + ln), (float)(qb + 16 + ln)};
  const float koffb = (float)(lg * 4);

  f4 st4[8];
  const int vk0  = (tid >> 2) * 2;
  const int vseg = (tid & 3) * 16;
  const int krow = (tid - 128) >> 1;
  const int kseg = ((tid - 128) & 1) * 32;
  const float* Vb = Vg + headoff;
  const float* Kb_ = Kg + headoff;

  auto stage_load = [&](int kv){
    const int kb = kv * KVBLK;
    if (tid < 128){
      const float* vp = Vb + (size_t)(kb + vk0) * DHEAD + vseg;
      st4[0] = *(const f4*)(vp);      st4[1] = *(const f4*)(vp + 4);
      st4[2] = *(const f4*)(vp + 8);  st4[3] = *(const f4*)(vp + 12);
      st4[4] = *(const f4*)(vp + 64); st4[5] = *(const f4*)(vp + 68);
      st4[6] = *(const f4*)(vp + 72); st4[7] = *(const f4*)(vp + 76);
    } else {
      const float* kp = Kb_ + (size_t)(kb + krow) * DHEAD + kseg;
#pragma unroll
      for (int j = 0; j < 8; ++j) st4[j] = *(const f4*)(kp + j*4);
    }
  };
  auto stage_store = [&](int b){
    if (tid < 128){
#pragma unroll
      for (int i = 0; i < 16; ++i){
        const int d = vseg + i;
        uint32_t pr = pk2(st4[i>>2][i&3], st4[4 + (i>>2)][i&3]);
        *(uint32_t*)&vbuf[b][(d*64 + vk0) ^ sw(d)] = pr;
      }
    } else {
#pragma unroll
      for (int i = 0; i < 4; ++i){
        union { uint32_t w[4]; s16x8 v; } u;
        u.w[0] = pk2(st4[i*2][0],   st4[i*2][1]);
        u.w[1] = pk2(st4[i*2][2],   st4[i*2][3]);
        u.w[2] = pk2(st4[i*2+1][0], st4[i*2+1][1]);
        u.w[3] = pk2(st4[i*2+1][2], st4[i*2+1][3]);
        *(s16x8*)&kbuf[b][(krow*64 + kseg + i*8) ^ sw(krow)] = u.v;
      }
    }
  };

  stage_load(0);
  stage_store(0);
  __syncthreads();
  int cur = 0;

#pragma unroll 1
  for (int kv = 0; kv < NT; ++kv){
    if (kv + 1 < NT) stage_load(kv + 1);

    const float kbf = (float)(kv * KVBLK);
    const u16* kb_ = kbuf[cur];
    const u16* vb_ = vbuf[cur];

    s16x8 kf[4][2];
#pragma unroll
    for (int kt = 0; kt < 4; ++kt){
      const int key = kt*16 + ln;
      const int sz  = sw(key);
      kf[kt][0] = *(const s16x8*)&kb_[(key*64 +      lg*8) ^ sz];
      kf[kt][1] = *(const s16x8*)&kb_[(key*64 + 32 + lg*8) ^ sz];
    }
    f32x4 S[2][4];
#pragma unroll
    for (int rg = 0; rg < 2; ++rg)
#pragma unroll
      for (int kt = 0; kt < 4; ++kt){
        f32x4 c = (f32x4)(0.0f);
        c = __builtin_amdgcn_mfma_f32_16x16x32_bf16(kf[kt][0], qf[rg][0], c, 0, 0, 0);
        c = __builtin_amdgcn_mfma_f32_16x16x32_bf16(kf[kt][1], qf[rg][1], c, 0, 0, 0);
        S[rg][kt] = c;
      }

    s16x4 pb[2][4];
#pragma unroll
    for (int rg = 0; rg < 2; ++rg){
      const float base = qposf[rg] - kbf - koffb;
#pragma unroll
      for (int kt = 0; kt < 4; ++kt)
#pragma unroll
        for (int r = 0; r < 4; ++r)
          S[rg][kt][r] = fmaf(-bs, fabsf(base - (float)(kt*16 + r)), S[rg][kt][r]);

      float a0 = fmaxf(fmaxf(S[rg][0][0], S[rg][0][1]), fmaxf(S[rg][0][2], S[rg][0][3]));
      float a1 = fmaxf(fmaxf(S[rg][1][0], S[rg][1][1]), fmaxf(S[rg][1][2], S[rg][1][3]));
      float a2 = fmaxf(fmaxf(S[rg][2][0], S[rg][2][1]), fmaxf(S[rg][2][2], S[rg][2][3]));
      float a3 = fmaxf(fmaxf(S[rg][3][0], S[rg][3][1]), fmaxf(S[rg][3][2], S[rg][3][3]));
      float mx = fmaxf(fmaxf(a0, a1), fmaxf(a2, a3));
      mx = fmaxf(mx, __shfl_xor(mx, 16, 64));
      mx = fmaxf(mx, __shfl_xor(mx, 32, 64));

      const float mo = mreg[rg];
      const float mn = fmaxf(mo, mx);
      const float scl = EXP2(mo - mn);
      mreg[rg] = mn;

      float p[16];
#pragma unroll
      for (int kt = 0; kt < 4; ++kt)
#pragma unroll
        for (int r = 0; r < 4; ++r)
          p[kt*4 + r] = EXP2(S[rg][kt][r] - mn);

      float s0 = (p[0]+p[1]) + (p[2]+p[3]);
      float s1 = (p[4]+p[5]) + (p[6]+p[7]);
      float s2 = (p[8]+p[9]) + (p[10]+p[11]);
      float s3 = (p[12]+p[13]) + (p[14]+p[15]);
      float sum = (s0+s1) + (s2+s3);
      sum += __shfl_xor(sum, 16, 64);
      sum += __shfl_xor(sum, 32, 64);
      lreg[rg] = lreg[rg] * scl + sum;

#pragma unroll
      for (int dt = 0; dt < 4; ++dt) acc[rg][dt] *= scl;

#pragma unroll
      for (int kt = 0; kt < 4; ++kt){
        union { uint32_t w[2]; s16x4 v; } u;
        u.w[0] = pk2(p[kt*4+0], p[kt*4+1]);
        u.w[1] = pk2(p[kt*4+2], p[kt*4+3]);
        pb[rg][kt] = u.v;
      }
    }

#pragma unroll
    for (int dt = 0; dt < 4; ++dt){
      const int d  = dt*16 + ln;
      const int sz = sw(d);
#pragma unroll
      for (int kt = 0; kt < 4; ++kt){
        const s16x4 vf = *(const s16x4*)&vb_[(d*64 + kt*16 + lg*4) ^ sz];
        acc[0][dt] = __builtin_amdgcn_mfma_f32_16x16x16bf16_1k(vf, pb[0][kt], acc[0][dt], 0, 0, 0);
        acc[1][dt] = __builtin_amdgcn_mfma_f32_16x16x16bf16_1k(vf, pb[1][kt], acc[1][dt], 0, 0, 0);
      }
    }

    if (kv + 1 < NT){
      stage_store(cur ^ 1);
      __syncthreads();
      cur ^= 1;
    }
  }

#pragma unroll
  for (int rg = 0; rg < 2; ++rg){
    const float inv = 1.0f / lreg[rg];
    float* op = Og + headoff + (size_t)(qb + rg*16 + ln) * DHEAD + lg*4;
#pragma unroll
    for (int dt = 0; dt < 4; ++dt){
      f4 o;
      o[0] = acc[rg][dt][0] * inv;
      o[1] = acc[rg][dt][1] * inv;
      o[2] = acc[rg][dt][2] * inv;
      o[3] = acc[rg][dt][3] * inv;
      *(f4*)(op + dt*16) = o;
    }
  }
}

extern "C" void kernel_launch(void* const* d_in, const int* in_sizes, int n_in,
                              void* d_out, int out_size, void* d_ws, size_t ws_size,
                              hipStream_t stream)
{
  const float* Q = (const float*)d_in[0];
  const float* K = (const float*)d_in[1];
  const float* V = (const float*)d_in[2];
  float* O = (float*)d_out;

  if (ws_size >= CHUNK_BYTES){
    u16* Kb = (u16*)d_ws;
    u16* VT = Kb + (size_t)NHEAD * T_LEN * DHEAD;
    float* part = (float*)((char*)d_ws + CONV_BYTES);
    hipLaunchKernelGGL(cvt_k,  dim3(2048), dim3(256), 0, stream, K, Kb);
    hipLaunchKernelGGL(cvt_vt, dim3(1024), dim3(256), 0, stream, V, VT);
    hipLaunchKernelGGL(alibi_attn5, dim3(2240), dim3(256), 0, stream, Q, Kb, VT, O, part);
    hipLaunchKernelGGL(combine_k, dim3(512), dim3(256), 0, stream, part, O);
  } else if (ws_size >= CONV_BYTES){
    u16* Kb = (u16*)d_ws;
    u16* VT = Kb + (size_t)NHEAD * T_LEN * DHEAD;
    hipLaunchKernelGGL(cvt_k,  dim3(2048), dim3(256), 0, stream, K, Kb);
    hipLaunchKernelGGL(cvt_vt, dim3(1024), dim3(256), 0, stream, V, VT);
    hipLaunchKernelGGL(alibi_attn4, dim3(1024), dim3(256), 0, stream, Q, Kb, VT, O);
  } else {
    hipLaunchKernelGGL(alibi_attn_fb, dim3(512), dim3(256), 0, stream, Q, K, V, O);
  }
}